// Round 6
// baseline (735.604 us; speedup 1.0000x reference)
//
#include <hip/hip_runtime.h>
#include <hip/hip_bf16.h>

#define H 128
#define SCAN_T 256
#define SCAN_I 8
#define SCAN_CHUNK (SCAN_T * SCAN_I)   // 2048 elems per scan block

typedef __bf16 bf16_t;
typedef __attribute__((ext_vector_type(2))) __bf16 bf16x2;
typedef __attribute__((ext_vector_type(8))) __bf16 bf16x8;
typedef __attribute__((ext_vector_type(4))) float f32x4;

static_assert(sizeof(bf16x8) == 16, "bf16x8 must be 16 bytes");

// f32 source -> A-fragment (8 bf16) for mfma_f32_16x16x32_bf16
__device__ inline bf16x8 load_a_frag_f32(const float* __restrict__ A, int row, int koff) {
    const float4* p = (const float4*)(A + (size_t)row * H + koff);
    float4 v0 = p[0], v1 = p[1];
    bf16x8 r;
    r[0] = (bf16_t)v0.x; r[1] = (bf16_t)v0.y; r[2] = (bf16_t)v0.z; r[3] = (bf16_t)v0.w;
    r[4] = (bf16_t)v1.x; r[5] = (bf16_t)v1.y; r[6] = (bf16_t)v1.z; r[7] = (bf16_t)v1.w;
    return r;
}

// ---------------- weight prep ----------------
__global__ void prep_weights(const float* __restrict__ Wf,  const float* __restrict__ Wih,
                             const float* __restrict__ Whh, const float* __restrict__ Wl1,
                             bf16_t* __restrict__ wfT, bf16_t* __restrict__ wih,
                             bf16_t* __restrict__ whh, bf16_t* __restrict__ wl1T) {
    int i = blockIdx.x * blockDim.x + threadIdx.x;
    if (i < 128 * 128) {
        int c = i >> 7, k = i & 127;
        wfT[i]  = (bf16_t)Wf[k * 128 + c];   // [k][c] -> [c][k]
        wl1T[i] = (bf16_t)Wl1[k * 128 + c];
    }
    if (i < 384 * 128) {
        wih[i] = (bf16_t)Wih[i];
        whh[i] = (bf16_t)Whh[i];
    }
}

// ---------------- CSR build ----------------
__global__ void hist_kernel(const int* __restrict__ ei, int* __restrict__ deg, int nE) {
    int e = blockIdx.x * blockDim.x + threadIdx.x;
    if (e < nE) atomicAdd(&deg[ei[nE + e]], 1);
}

__global__ __launch_bounds__(SCAN_T) void scan1_kernel(
    const int* __restrict__ deg, int* __restrict__ rowptr, int* __restrict__ bsum, int n) {
    __shared__ int s[SCAN_T];
    int base = blockIdx.x * SCAN_CHUNK + threadIdx.x * SCAN_I;
    int v[SCAN_I];
    int sum = 0;
    for (int j = 0; j < SCAN_I; ++j) {
        int idx = base + j;
        v[j] = (idx < n) ? deg[idx] : 0;
        sum += v[j];
    }
    s[threadIdx.x] = sum;
    __syncthreads();
    for (int off = 1; off < SCAN_T; off <<= 1) {
        int t = (threadIdx.x >= off) ? s[threadIdx.x - off] : 0;
        __syncthreads();
        s[threadIdx.x] += t;
        __syncthreads();
    }
    int run = s[threadIdx.x] - sum;
    for (int j = 0; j < SCAN_I; ++j) {
        int idx = base + j;
        if (idx < n) rowptr[idx] = run;
        run += v[j];
    }
    if (threadIdx.x == SCAN_T - 1) bsum[blockIdx.x] = s[SCAN_T - 1];
}

__global__ __launch_bounds__(SCAN_T) void scan2_kernel(int* __restrict__ bsum, int nb) {
    __shared__ int s[SCAN_T];
    int v = (threadIdx.x < nb) ? bsum[threadIdx.x] : 0;
    s[threadIdx.x] = v;
    __syncthreads();
    for (int off = 1; off < SCAN_T; off <<= 1) {
        int t = (threadIdx.x >= off) ? s[threadIdx.x - off] : 0;
        __syncthreads();
        s[threadIdx.x] += t;
        __syncthreads();
    }
    if (threadIdx.x < nb) bsum[threadIdx.x] = s[threadIdx.x] - v;
}

__global__ void scan3_kernel(int* __restrict__ rowptr, int* __restrict__ cursor,
                             const int* __restrict__ bsum, int n, int nE) {
    int idx = blockIdx.x * blockDim.x + threadIdx.x;
    if (idx < n) {
        int val = rowptr[idx] + bsum[idx / SCAN_CHUNK];
        rowptr[idx] = val;
        cursor[idx] = val;
    }
    if (idx == 0) rowptr[n] = nE;
}

// XCD-bucketed scatter: block r=bid&7 handles dst range [r*n/8, (r+1)*n/8).
// Blocks on the same XCD (round-robin dispatch heuristic) write a 1.6MB region
// that fits the per-XCD 4MB L2 -> lines fill before eviction (write ~= payload).
__global__ __launch_bounds__(256) void scatter_kernel(
    const int* __restrict__ ei, const float* __restrict__ ew,
    int* __restrict__ cursor, int2* __restrict__ srcw, int nE, int n) {
    int r = blockIdx.x & 7;
    int nslice = n >> 3;                 // n divisible by 8 (100000/8=12500)
    int lo = r * nslice;
    int hi = (r == 7) ? n : lo + nslice;
    int chunk = blockIdx.x >> 3;
    int nchunk = gridDim.x >> 3;
    for (int e = chunk * 256 + threadIdx.x; e < nE; e += nchunk * 256) {
        int dst = ei[nE + e];
        if (dst >= lo && dst < hi) {
            int pos = atomicAdd(&cursor[dst], 1);
            srcw[pos] = make_int2(ei[e], __float_as_int(ew[e]));
        }
    }
}

// ---------------- gated conv via CSR: 4 edges in flight per wave ----------------
__device__ inline void conv_fma(float* acc, uint4 u, float w) {
    acc[0] += __uint_as_float(u.x << 16) * w;
    acc[1] += __uint_as_float(u.x & 0xffff0000u) * w;
    acc[2] += __uint_as_float(u.y << 16) * w;
    acc[3] += __uint_as_float(u.y & 0xffff0000u) * w;
    acc[4] += __uint_as_float(u.z << 16) * w;
    acc[5] += __uint_as_float(u.z & 0xffff0000u) * w;
    acc[6] += __uint_as_float(u.w << 16) * w;
    acc[7] += __uint_as_float(u.w & 0xffff0000u) * w;
}

__global__ __launch_bounds__(256) void conv_csr_kernel(
    const bf16_t* __restrict__ xb, const int* __restrict__ rowptr,
    const int2* __restrict__ srcw, bf16_t* __restrict__ agg, int n) {
    int lane = threadIdx.x & 63;
    int d = (blockIdx.x * blockDim.x + threadIdx.x) >> 6;
    if (d >= n) return;
    int q = lane >> 4;        // edge slot 0..3
    int l = lane & 15;        // channel group: cols 8l..8l+7
    int beg = rowptr[d], end = rowptr[d + 1];

    float acc[8];
    #pragma unroll
    for (int i = 0; i < 8; ++i) acc[i] = 0.f;

    int e = beg + q;
    for (; e + 4 < end; e += 8) {
        int2 sw0 = srcw[e];
        int2 sw1 = srcw[e + 4];
        uint4 u0 = *(const uint4*)(xb + (size_t)sw0.x * H + l * 8);
        uint4 u1 = *(const uint4*)(xb + (size_t)sw1.x * H + l * 8);
        conv_fma(acc, u0, __int_as_float(sw0.y));
        conv_fma(acc, u1, __int_as_float(sw1.y));
    }
    if (e < end) {
        int2 sw = srcw[e];
        uint4 u = *(const uint4*)(xb + (size_t)sw.x * H + l * 8);
        conv_fma(acc, u, __int_as_float(sw.y));
    }

    #pragma unroll
    for (int i = 0; i < 8; ++i) {
        acc[i] += __shfl_xor(acc[i], 16);
        acc[i] += __shfl_xor(acc[i], 32);
    }
    if (q == 0) {
        bf16x8 r;
        #pragma unroll
        for (int i = 0; i < 8; ++i) r[i] = (bf16_t)acc[i];
        *(bf16x8*)(agg + (size_t)d * H + l * 8) = r;
    }
}

// ---------------- lin kernels: whole 32KB weight staged in LDS (swizzled) ----------------
// 16B granule (row, seg) -> byte row*256 + ((seg*16) ^ ((row&7)<<4))

// first lin: A f32 -> out bf16
__global__ __launch_bounds__(256) void lin_first_kernel(
    const float* __restrict__ A, const bf16_t* __restrict__ Bt,
    const float* __restrict__ bias, bf16_t* __restrict__ outb, int n) {
    __shared__ __align__(16) unsigned char wlds[32768];
    int tid = threadIdx.x;
    int wid = tid >> 6, lane = tid & 63;
    int r0 = (blockIdx.x * 4 + wid) * 32;
    int lrow = lane & 15, lq = lane >> 4, lk8 = lq * 8;

    #pragma unroll
    for (int i = 0; i < 8; ++i) {
        int g = i * 256 + tid;
        int row = g >> 4, seg = g & 15;
        uint4 v = *(const uint4*)(Bt + row * 128 + seg * 8);
        *(uint4*)(&wlds[row * 256 + ((seg * 16) ^ ((row & 7) << 4))]) = v;
    }

    bf16x8 a[2][4];
    for (int rt = 0; rt < 2; ++rt) {
        int row = r0 + rt * 16 + lrow;
        if (row >= n) row = n - 1;
        for (int t = 0; t < 4; ++t) a[rt][t] = load_a_frag_f32(A, row, t * 32 + lk8);
    }
    __syncthreads();

    for (int ct = 0; ct < 8; ++ct) {
        int c0 = ct * 16;
        f32x4 acc0 = {0.f, 0.f, 0.f, 0.f}, acc1 = {0.f, 0.f, 0.f, 0.f};
        int rbase = (c0 + lrow) * 256;
        int sw = (lrow & 7) << 4;
        #pragma unroll
        for (int t = 0; t < 4; ++t) {
            bf16x8 b = *(const bf16x8*)(&wlds[rbase + ((t * 64 + lq * 16) ^ sw)]);
            acc0 = __builtin_amdgcn_mfma_f32_16x16x32_bf16(a[0][t], b, acc0, 0, 0, 0);
            acc1 = __builtin_amdgcn_mfma_f32_16x16x32_bf16(a[1][t], b, acc1, 0, 0, 0);
        }
        int col = c0 + lrow;
        float bv = bias[col];
        for (int r = 0; r < 4; ++r) {
            int row0 = r0 + lq * 4 + r;
            if (row0 < n) outb[(size_t)row0 * H + col] = (bf16_t)(acc0[r] + bv);
            int row1 = row0 + 16;
            if (row1 < n) outb[(size_t)row1 * H + col] = (bf16_t)(acc1[r] + bv);
        }
    }
}

// mid lin: A bf16 -> out bf16
__global__ __launch_bounds__(256) void lin_mid_kernel(
    const bf16_t* __restrict__ A, const bf16_t* __restrict__ Bt,
    const float* __restrict__ bias, bf16_t* __restrict__ out, int n) {
    __shared__ __align__(16) unsigned char wlds[32768];
    int tid = threadIdx.x;
    int wid = tid >> 6, lane = tid & 63;
    int r0 = (blockIdx.x * 4 + wid) * 32;
    int lrow = lane & 15, lq = lane >> 4, lk8 = lq * 8;

    #pragma unroll
    for (int i = 0; i < 8; ++i) {
        int g = i * 256 + tid;
        int row = g >> 4, seg = g & 15;
        uint4 v = *(const uint4*)(Bt + row * 128 + seg * 8);
        *(uint4*)(&wlds[row * 256 + ((seg * 16) ^ ((row & 7) << 4))]) = v;
    }

    bf16x8 a[2][4];
    for (int rt = 0; rt < 2; ++rt) {
        int row = r0 + rt * 16 + lrow;
        if (row >= n) row = n - 1;
        for (int t = 0; t < 4; ++t)
            a[rt][t] = *(const bf16x8*)(A + (size_t)row * H + t * 32 + lk8);
    }
    __syncthreads();

    for (int ct = 0; ct < 8; ++ct) {
        int c0 = ct * 16;
        f32x4 acc0 = {0.f, 0.f, 0.f, 0.f}, acc1 = {0.f, 0.f, 0.f, 0.f};
        int rbase = (c0 + lrow) * 256;
        int sw = (lrow & 7) << 4;
        #pragma unroll
        for (int t = 0; t < 4; ++t) {
            bf16x8 b = *(const bf16x8*)(&wlds[rbase + ((t * 64 + lq * 16) ^ sw)]);
            acc0 = __builtin_amdgcn_mfma_f32_16x16x32_bf16(a[0][t], b, acc0, 0, 0, 0);
            acc1 = __builtin_amdgcn_mfma_f32_16x16x32_bf16(a[1][t], b, acc1, 0, 0, 0);
        }
        int col = c0 + lrow;
        float bv = bias[col];
        for (int r = 0; r < 4; ++r) {
            int row0 = r0 + lq * 4 + r;
            if (row0 < n) out[(size_t)row0 * H + col] = (bf16_t)(acc0[r] + bv);
            int row1 = row0 + 16;
            if (row1 < n) out[(size_t)row1 * H + col] = (bf16_t)(acc1[r] + bv);
        }
    }
}

// ---------------- fused GRU cell: single-buffer LDS weight staging ----------------
// hid recovered at C-layout via identity-MFMA from ah fragments (no f32 hidden buffer).
template<bool LOGITS>
__global__ __launch_bounds__(256) void gru_kernel(
    const bf16_t* __restrict__ inp, const bf16_t* __restrict__ hidb,
    const bf16_t* __restrict__ Wih, const bf16_t* __restrict__ Whh,
    const float* __restrict__ bih, const float* __restrict__ bhh,
    bf16_t* __restrict__ out, const float* __restrict__ Wo,
    const float* __restrict__ bo, float* __restrict__ logits, int n) {
    __shared__ __align__(16) unsigned char wlds[6 * 4096];
    int tid = threadIdx.x;
    int wid = tid >> 6, lane = tid & 63;
    int r0 = (blockIdx.x * 4 + wid) * 32;
    int lrow = lane & 15, lq = lane >> 4, lk8 = lq * 8;

    // staging: thread -> one 16B granule per slab (coalesced global, swizzled LDS)
    int srow = tid >> 4, sseg = tid & 15;
    int s_src = srow * 128 + sseg * 8;
    int s_lds = srow * 256 + ((sseg * 16) ^ ((srow & 7) << 4));

    bf16x8 ai[2][4], ah[2][4];
    for (int rt = 0; rt < 2; ++rt) {
        int row = r0 + rt * 16 + lrow;
        if (row >= n) row = n - 1;
        for (int t = 0; t < 4; ++t) {
            ai[rt][t] = *(const bf16x8*)(inp  + (size_t)row * H + t * 32 + lk8);
            ah[rt][t] = *(const bf16x8*)(hidb + (size_t)row * H + t * 32 + lk8);
        }
    }

    float s0[2][4], s1[2][4];
    if (LOGITS) {
        for (int rt = 0; rt < 2; ++rt)
            for (int r = 0; r < 4; ++r) { s0[rt][r] = 0.f; s1[rt][r] = 0.f; }
    }

    for (int ct = 0; ct < 8; ++ct) {
        // straight-line staging: 6 named regs, no arrays, no lambdas
        uint4 u0 = *(const uint4*)(Wih + (size_t)(0 * 128 + ct * 16) * 128 + s_src);
        uint4 u1 = *(const uint4*)(Wih + (size_t)(1 * 128 + ct * 16) * 128 + s_src);
        uint4 u2 = *(const uint4*)(Wih + (size_t)(2 * 128 + ct * 16) * 128 + s_src);
        uint4 u3 = *(const uint4*)(Whh + (size_t)(0 * 128 + ct * 16) * 128 + s_src);
        uint4 u4 = *(const uint4*)(Whh + (size_t)(1 * 128 + ct * 16) * 128 + s_src);
        uint4 u5 = *(const uint4*)(Whh + (size_t)(2 * 128 + ct * 16) * 128 + s_src);
        __syncthreads();                       // all waves done reading previous ct
        *(uint4*)(&wlds[0 * 4096 + s_lds]) = u0;
        *(uint4*)(&wlds[1 * 4096 + s_lds]) = u1;
        *(uint4*)(&wlds[2 * 4096 + s_lds]) = u2;
        *(uint4*)(&wlds[3 * 4096 + s_lds]) = u3;
        *(uint4*)(&wlds[4 * 4096 + s_lds]) = u4;
        *(uint4*)(&wlds[5 * 4096 + s_lds]) = u5;
        __syncthreads();                       // staged data visible

        int col = ct * 16 + lrow;
        f32x4 air[2], aiz[2], ain[2], ahr[2], ahz[2], ahn[2];
        for (int rt = 0; rt < 2; ++rt) {
            air[rt] = (f32x4){0.f,0.f,0.f,0.f}; aiz[rt] = (f32x4){0.f,0.f,0.f,0.f};
            ain[rt] = (f32x4){0.f,0.f,0.f,0.f}; ahr[rt] = (f32x4){0.f,0.f,0.f,0.f};
            ahz[rt] = (f32x4){0.f,0.f,0.f,0.f}; ahn[rt] = (f32x4){0.f,0.f,0.f,0.f};
        }
        int rbase = lrow * 256;
        int sw = (lrow & 7) << 4;
        #pragma unroll
        for (int t = 0; t < 4; ++t) {
            int roff = rbase + ((t * 64 + lq * 16) ^ sw);
            bf16x8 bir = *(const bf16x8*)(&wlds[0 * 4096 + roff]);
            bf16x8 biz = *(const bf16x8*)(&wlds[1 * 4096 + roff]);
            bf16x8 bin = *(const bf16x8*)(&wlds[2 * 4096 + roff]);
            bf16x8 bhr = *(const bf16x8*)(&wlds[3 * 4096 + roff]);
            bf16x8 bhz = *(const bf16x8*)(&wlds[4 * 4096 + roff]);
            bf16x8 bhn = *(const bf16x8*)(&wlds[5 * 4096 + roff]);
            for (int rt = 0; rt < 2; ++rt) {
                air[rt] = __builtin_amdgcn_mfma_f32_16x16x32_bf16(ai[rt][t], bir, air[rt], 0, 0, 0);
                aiz[rt] = __builtin_amdgcn_mfma_f32_16x16x32_bf16(ai[rt][t], biz, aiz[rt], 0, 0, 0);
                ain[rt] = __builtin_amdgcn_mfma_f32_16x16x32_bf16(ai[rt][t], bin, ain[rt], 0, 0, 0);
                ahr[rt] = __builtin_amdgcn_mfma_f32_16x16x32_bf16(ah[rt][t], bhr, ahr[rt], 0, 0, 0);
                ahz[rt] = __builtin_amdgcn_mfma_f32_16x16x32_bf16(ah[rt][t], bhz, ahz[rt], 0, 0, 0);
                ahn[rt] = __builtin_amdgcn_mfma_f32_16x16x32_bf16(ah[rt][t], bhn, ahn[rt], 0, 0, 0);
            }
        }

        // hid at C-layout via identity-MFMA: D = hid @ I  (exact x1.0)
        int idx = ((ct & 1) << 4) | lrow;         // k-offset within t-tile ct>>1
        bf16x8 bid;
        #pragma unroll
        for (int j = 0; j < 8; ++j)
            bid[j] = (bf16_t)((lq == (idx >> 3) && j == (idx & 7)) ? 1.f : 0.f);
        int tct = ct >> 1;
        f32x4 hc[2];
        for (int rt = 0; rt < 2; ++rt) {
            f32x4 z = {0.f, 0.f, 0.f, 0.f};
            hc[rt] = __builtin_amdgcn_mfma_f32_16x16x32_bf16(ah[rt][tct], bid, z, 0, 0, 0);
        }

        float b_ir = bih[col], b_iz = bih[128 + col], b_in = bih[256 + col];
        float b_hr = bhh[col], b_hz = bhh[128 + col], b_hn = bhh[256 + col];
        float w0 = 0.f, w1 = 0.f;
        if (LOGITS) { float2 wv = *(const float2*)(Wo + col * 2); w0 = wv.x; w1 = wv.y; }
        for (int rt = 0; rt < 2; ++rt) {
            for (int r = 0; r < 4; ++r) {
                int row = r0 + rt * 16 + lq * 4 + r;
                float irv = air[rt][r] + b_ir, hrv = ahr[rt][r] + b_hr;
                float izv = aiz[rt][r] + b_iz, hzv = ahz[rt][r] + b_hz;
                float inv = ain[rt][r] + b_in, hnv = ahn[rt][r] + b_hn;
                float rg = 1.f / (1.f + __expf(-(irv + hrv)));
                float zg = 1.f / (1.f + __expf(-(izv + hzv)));
                float xx = inv + rg * hnv;
                float ng = 2.f / (1.f + __expf(-2.f * xx)) - 1.f;   // tanh
                float hv = hc[rt][r];
                float hout = (1.f - zg) * ng + zg * hv;
                if (LOGITS) {
                    s0[rt][r] += hout * w0;
                    s1[rt][r] += hout * w1;
                } else if (row < n) {
                    out[(size_t)row * H + col] = (bf16_t)hout;
                }
            }
        }
    }

    if (LOGITS) {
        for (int m = 1; m < 16; m <<= 1) {
            for (int rt = 0; rt < 2; ++rt)
                for (int r = 0; r < 4; ++r) {
                    s0[rt][r] += __shfl_xor(s0[rt][r], m);
                    s1[rt][r] += __shfl_xor(s1[rt][r], m);
                }
        }
        if (lrow == 0) {
            float bo0 = bo[0], bo1 = bo[1];
            for (int rt = 0; rt < 2; ++rt)
                for (int r = 0; r < 4; ++r) {
                    int row = r0 + rt * 16 + lq * 4 + r;
                    if (row < n) {
                        float l0 = s0[rt][r] + bo0, l1 = s1[rt][r] + bo1;
                        float mx = fmaxf(l0, l1);
                        float lse = mx + __logf(__expf(l0 - mx) + __expf(l1 - mx));
                        logits[(size_t)row * 2]     = l0 - lse;
                        logits[(size_t)row * 2 + 1] = l1 - lse;
                    }
                }
        }
    }
}

extern "C" void kernel_launch(void* const* d_in, const int* in_sizes, int n_in,
                              void* d_out, int out_size, void* d_ws, size_t ws_size,
                              hipStream_t stream) {
    const float* x   = (const float*)d_in[0];
    const int*   ei  = (const int*)d_in[1];
    const float* ew  = (const float*)d_in[2];
    const float* Wf  = (const float*)d_in[3];
    const float* bf  = (const float*)d_in[4];
    const float* Wih = (const float*)d_in[5];
    const float* bih = (const float*)d_in[6];
    const float* Whh = (const float*)d_in[7];
    const float* bhh = (const float*)d_in[8];
    const float* Wl1 = (const float*)d_in[9];
    const float* bl1 = (const float*)d_in[10];
    const float* Wo  = (const float*)d_in[11];
    const float* bo  = (const float*)d_in[12];

    int n  = in_sizes[0] / H;     // 100000
    int nE = in_sizes[2];         // 1600000

    bf16_t* hbufb = (bf16_t*)d_ws;                        // [n][H] bf16 hidden
    bf16_t* b1b   = hbufb + (size_t)n * H;                // [n][H] bf16
    bf16_t* b2b   = b1b + (size_t)n * H;                  // [n][H] bf16
    bf16_t* wfT   = b2b + (size_t)n * H;
    bf16_t* wih   = wfT + 128 * 128;
    bf16_t* whh   = wih + 384 * 128;
    bf16_t* wl1T  = whh + 384 * 128;
    int* deg    = (int*)(wl1T + 128 * 128);               // [n]
    int* rowptr = deg + n;                                // [n+1]
    int* cursor = rowptr + (n + 1);                       // [n]
    int2* srcw  = (int2*)((char*)(cursor + n) + ((size_t)(-(intptr_t)(cursor + n)) & 7)); // [nE]

    int gemmGrid = (n + 127) / 128;
    int nScanBlocks = (n + SCAN_CHUNK - 1) / SCAN_CHUNK;

    // ---- weights + CSR build ----
    prep_weights<<<192, 256, 0, stream>>>(Wf, Wih, Whh, Wl1, wfT, wih, whh, wl1T);
    hipMemsetAsync(deg, 0, (size_t)n * sizeof(int), stream);
    hist_kernel<<<(nE + 255) / 256, 256, 0, stream>>>(ei, deg, nE);
    scan1_kernel<<<nScanBlocks, SCAN_T, 0, stream>>>(deg, rowptr, cursor, n);
    scan2_kernel<<<1, SCAN_T, 0, stream>>>(cursor, nScanBlocks);
    scan3_kernel<<<(n + 255) / 256, 256, 0, stream>>>(rowptr, deg, cursor, n, nE);
    scatter_kernel<<<2048, 256, 0, stream>>>(ei, ew, deg, srcw, nE, n);

    // ---- pipeline ----
    lin_first_kernel<<<gemmGrid, 256, 0, stream>>>(x, wfT, bf, hbufb, n);
    conv_csr_kernel<<<(n + 3) / 4, 256, 0, stream>>>(hbufb, rowptr, srcw, b1b, n);
    gru_kernel<false><<<gemmGrid, 256, 0, stream>>>(b1b, hbufb, wih, whh, bih, bhh,
                                                    b1b, nullptr, nullptr, nullptr, n);
    lin_mid_kernel<<<gemmGrid, 256, 0, stream>>>(b1b, wl1T, bl1, b2b, n);
    conv_csr_kernel<<<(n + 3) / 4, 256, 0, stream>>>(b2b, rowptr, srcw, b1b, n);
    gru_kernel<true><<<gemmGrid, 256, 0, stream>>>(b1b, hbufb, wih, whh, bih, bhh,
                                                   nullptr, Wo, bo, (float*)d_out, n);
}

// Round 7
// 664.656 us; speedup vs baseline: 1.1067x; 1.1067x over previous
//
#include <hip/hip_runtime.h>
#include <hip/hip_bf16.h>

#define H 128
#define SCAN_T 256
#define SCAN_I 8
#define SCAN_CHUNK (SCAN_T * SCAN_I)   // 2048 elems per scan block
#define GRU_RB 196                     // row-blocks; gru grid = 4 * GRU_RB

typedef __bf16 bf16_t;
typedef __attribute__((ext_vector_type(2))) __bf16 bf16x2;
typedef __attribute__((ext_vector_type(8))) __bf16 bf16x8;
typedef __attribute__((ext_vector_type(4))) float f32x4;

static_assert(sizeof(bf16x8) == 16, "bf16x8 must be 16 bytes");

// f32 source -> A-fragment (8 bf16) for mfma_f32_16x16x32_bf16
__device__ inline bf16x8 load_a_frag_f32(const float* __restrict__ A, int row, int koff) {
    const float4* p = (const float4*)(A + (size_t)row * H + koff);
    float4 v0 = p[0], v1 = p[1];
    bf16x8 r;
    r[0] = (bf16_t)v0.x; r[1] = (bf16_t)v0.y; r[2] = (bf16_t)v0.z; r[3] = (bf16_t)v0.w;
    r[4] = (bf16_t)v1.x; r[5] = (bf16_t)v1.y; r[6] = (bf16_t)v1.z; r[7] = (bf16_t)v1.w;
    return r;
}

// ---------------- weight prep ----------------
__global__ void prep_weights(const float* __restrict__ Wf,  const float* __restrict__ Wih,
                             const float* __restrict__ Whh, const float* __restrict__ Wl1,
                             bf16_t* __restrict__ wfT, bf16_t* __restrict__ wih,
                             bf16_t* __restrict__ whh, bf16_t* __restrict__ wl1T) {
    int i = blockIdx.x * blockDim.x + threadIdx.x;
    if (i < 128 * 128) {
        int c = i >> 7, k = i & 127;
        wfT[i]  = (bf16_t)Wf[k * 128 + c];   // [k][c] -> [c][k]
        wl1T[i] = (bf16_t)Wl1[k * 128 + c];
    }
    if (i < 384 * 128) {
        wih[i] = (bf16_t)Wih[i];
        whh[i] = (bf16_t)Whh[i];
    }
}

// ---------------- CSR build ----------------
__global__ void hist_kernel(const int* __restrict__ ei, int* __restrict__ deg, int nE) {
    int e = blockIdx.x * blockDim.x + threadIdx.x;
    if (e < nE) atomicAdd(&deg[ei[nE + e]], 1);
}

__global__ __launch_bounds__(SCAN_T) void scan1_kernel(
    const int* __restrict__ deg, int* __restrict__ rowptr, int* __restrict__ bsum, int n) {
    __shared__ int s[SCAN_T];
    int base = blockIdx.x * SCAN_CHUNK + threadIdx.x * SCAN_I;
    int v[SCAN_I];
    int sum = 0;
    for (int j = 0; j < SCAN_I; ++j) {
        int idx = base + j;
        v[j] = (idx < n) ? deg[idx] : 0;
        sum += v[j];
    }
    s[threadIdx.x] = sum;
    __syncthreads();
    for (int off = 1; off < SCAN_T; off <<= 1) {
        int t = (threadIdx.x >= off) ? s[threadIdx.x - off] : 0;
        __syncthreads();
        s[threadIdx.x] += t;
        __syncthreads();
    }
    int run = s[threadIdx.x] - sum;
    for (int j = 0; j < SCAN_I; ++j) {
        int idx = base + j;
        if (idx < n) rowptr[idx] = run;
        run += v[j];
    }
    if (threadIdx.x == SCAN_T - 1) bsum[blockIdx.x] = s[SCAN_T - 1];
}

__global__ __launch_bounds__(SCAN_T) void scan2_kernel(int* __restrict__ bsum, int nb) {
    __shared__ int s[SCAN_T];
    int v = (threadIdx.x < nb) ? bsum[threadIdx.x] : 0;
    s[threadIdx.x] = v;
    __syncthreads();
    for (int off = 1; off < SCAN_T; off <<= 1) {
        int t = (threadIdx.x >= off) ? s[threadIdx.x - off] : 0;
        __syncthreads();
        s[threadIdx.x] += t;
        __syncthreads();
    }
    if (threadIdx.x < nb) bsum[threadIdx.x] = s[threadIdx.x] - v;
}

__global__ void scan3_kernel(int* __restrict__ rowptr, int* __restrict__ cursor,
                             const int* __restrict__ bsum, int n, int nE) {
    int idx = blockIdx.x * blockDim.x + threadIdx.x;
    if (idx < n) {
        int val = rowptr[idx] + bsum[idx / SCAN_CHUNK];
        rowptr[idx] = val;
        cursor[idx] = val;
    }
    if (idx == 0) rowptr[n] = nE;
}

// XCD-bucketed scatter: block r=bid&7 handles dst range [r*n/8, (r+1)*n/8).
__global__ __launch_bounds__(256) void scatter_kernel(
    const int* __restrict__ ei, const float* __restrict__ ew,
    int* __restrict__ cursor, int2* __restrict__ srcw, int nE, int n) {
    int r = blockIdx.x & 7;
    int nslice = n >> 3;
    int lo = r * nslice;
    int hi = (r == 7) ? n : lo + nslice;
    int chunk = blockIdx.x >> 3;
    int nchunk = gridDim.x >> 3;
    for (int e = chunk * 256 + threadIdx.x; e < nE; e += nchunk * 256) {
        int dst = ei[nE + e];
        if (dst >= lo && dst < hi) {
            int pos = atomicAdd(&cursor[dst], 1);
            srcw[pos] = make_int2(ei[e], __float_as_int(ew[e]));
        }
    }
}

// ---------------- gated conv via CSR: 4 edges in flight per wave ----------------
__device__ inline void conv_fma(float* acc, uint4 u, float w) {
    acc[0] += __uint_as_float(u.x << 16) * w;
    acc[1] += __uint_as_float(u.x & 0xffff0000u) * w;
    acc[2] += __uint_as_float(u.y << 16) * w;
    acc[3] += __uint_as_float(u.y & 0xffff0000u) * w;
    acc[4] += __uint_as_float(u.z << 16) * w;
    acc[5] += __uint_as_float(u.z & 0xffff0000u) * w;
    acc[6] += __uint_as_float(u.w << 16) * w;
    acc[7] += __uint_as_float(u.w & 0xffff0000u) * w;
}

__global__ __launch_bounds__(256) void conv_csr_kernel(
    const bf16_t* __restrict__ xb, const int* __restrict__ rowptr,
    const int2* __restrict__ srcw, bf16_t* __restrict__ agg, int n) {
    int lane = threadIdx.x & 63;
    int d = (blockIdx.x * blockDim.x + threadIdx.x) >> 6;
    if (d >= n) return;
    int q = lane >> 4;
    int l = lane & 15;
    int beg = rowptr[d], end = rowptr[d + 1];

    float acc[8];
    #pragma unroll
    for (int i = 0; i < 8; ++i) acc[i] = 0.f;

    int e = beg + q;
    for (; e + 4 < end; e += 8) {
        int2 sw0 = srcw[e];
        int2 sw1 = srcw[e + 4];
        uint4 u0 = *(const uint4*)(xb + (size_t)sw0.x * H + l * 8);
        uint4 u1 = *(const uint4*)(xb + (size_t)sw1.x * H + l * 8);
        conv_fma(acc, u0, __int_as_float(sw0.y));
        conv_fma(acc, u1, __int_as_float(sw1.y));
    }
    if (e < end) {
        int2 sw = srcw[e];
        uint4 u = *(const uint4*)(xb + (size_t)sw.x * H + l * 8);
        conv_fma(acc, u, __int_as_float(sw.y));
    }

    #pragma unroll
    for (int i = 0; i < 8; ++i) {
        acc[i] += __shfl_xor(acc[i], 16);
        acc[i] += __shfl_xor(acc[i], 32);
    }
    if (q == 0) {
        bf16x8 r;
        #pragma unroll
        for (int i = 0; i < 8; ++i) r[i] = (bf16_t)acc[i];
        *(bf16x8*)(agg + (size_t)d * H + l * 8) = r;
    }
}

// ---------------- lin kernels: whole 32KB weight staged in LDS (swizzled) ----------------
// 16B granule (row, seg) -> byte row*256 + ((seg*16) ^ ((row&7)<<4))

__global__ __launch_bounds__(256) void lin_first_kernel(
    const float* __restrict__ A, const bf16_t* __restrict__ Bt,
    const float* __restrict__ bias, bf16_t* __restrict__ outb, int n) {
    __shared__ __align__(16) unsigned char wlds[32768];
    int tid = threadIdx.x;
    int wid = tid >> 6, lane = tid & 63;
    int r0 = (blockIdx.x * 4 + wid) * 32;
    int lrow = lane & 15, lq = lane >> 4, lk8 = lq * 8;

    #pragma unroll
    for (int i = 0; i < 8; ++i) {
        int g = i * 256 + tid;
        int row = g >> 4, seg = g & 15;
        uint4 v = *(const uint4*)(Bt + row * 128 + seg * 8);
        *(uint4*)(&wlds[row * 256 + ((seg * 16) ^ ((row & 7) << 4))]) = v;
    }

    bf16x8 a[2][4];
    for (int rt = 0; rt < 2; ++rt) {
        int row = r0 + rt * 16 + lrow;
        if (row >= n) row = n - 1;
        for (int t = 0; t < 4; ++t) a[rt][t] = load_a_frag_f32(A, row, t * 32 + lk8);
    }
    __syncthreads();

    for (int ct = 0; ct < 8; ++ct) {
        int c0 = ct * 16;
        f32x4 acc0 = {0.f, 0.f, 0.f, 0.f}, acc1 = {0.f, 0.f, 0.f, 0.f};
        int rbase = (c0 + lrow) * 256;
        int sw = (lrow & 7) << 4;
        #pragma unroll
        for (int t = 0; t < 4; ++t) {
            bf16x8 b = *(const bf16x8*)(&wlds[rbase + ((t * 64 + lq * 16) ^ sw)]);
            acc0 = __builtin_amdgcn_mfma_f32_16x16x32_bf16(a[0][t], b, acc0, 0, 0, 0);
            acc1 = __builtin_amdgcn_mfma_f32_16x16x32_bf16(a[1][t], b, acc1, 0, 0, 0);
        }
        int col = c0 + lrow;
        float bv = bias[col];
        for (int r = 0; r < 4; ++r) {
            int row0 = r0 + lq * 4 + r;
            if (row0 < n) outb[(size_t)row0 * H + col] = (bf16_t)(acc0[r] + bv);
            int row1 = row0 + 16;
            if (row1 < n) outb[(size_t)row1 * H + col] = (bf16_t)(acc1[r] + bv);
        }
    }
}

__global__ __launch_bounds__(256) void lin_mid_kernel(
    const bf16_t* __restrict__ A, const bf16_t* __restrict__ Bt,
    const float* __restrict__ bias, bf16_t* __restrict__ out, int n) {
    __shared__ __align__(16) unsigned char wlds[32768];
    int tid = threadIdx.x;
    int wid = tid >> 6, lane = tid & 63;
    int r0 = (blockIdx.x * 4 + wid) * 32;
    int lrow = lane & 15, lq = lane >> 4, lk8 = lq * 8;

    #pragma unroll
    for (int i = 0; i < 8; ++i) {
        int g = i * 256 + tid;
        int row = g >> 4, seg = g & 15;
        uint4 v = *(const uint4*)(Bt + row * 128 + seg * 8);
        *(uint4*)(&wlds[row * 256 + ((seg * 16) ^ ((row & 7) << 4))]) = v;
    }

    bf16x8 a[2][4];
    for (int rt = 0; rt < 2; ++rt) {
        int row = r0 + rt * 16 + lrow;
        if (row >= n) row = n - 1;
        for (int t = 0; t < 4; ++t)
            a[rt][t] = *(const bf16x8*)(A + (size_t)row * H + t * 32 + lk8);
    }
    __syncthreads();

    for (int ct = 0; ct < 8; ++ct) {
        int c0 = ct * 16;
        f32x4 acc0 = {0.f, 0.f, 0.f, 0.f}, acc1 = {0.f, 0.f, 0.f, 0.f};
        int rbase = (c0 + lrow) * 256;
        int sw = (lrow & 7) << 4;
        #pragma unroll
        for (int t = 0; t < 4; ++t) {
            bf16x8 b = *(const bf16x8*)(&wlds[rbase + ((t * 64 + lq * 16) ^ sw)]);
            acc0 = __builtin_amdgcn_mfma_f32_16x16x32_bf16(a[0][t], b, acc0, 0, 0, 0);
            acc1 = __builtin_amdgcn_mfma_f32_16x16x32_bf16(a[1][t], b, acc1, 0, 0, 0);
        }
        int col = c0 + lrow;
        float bv = bias[col];
        for (int r = 0; r < 4; ++r) {
            int row0 = r0 + lq * 4 + r;
            if (row0 < n) out[(size_t)row0 * H + col] = (bf16_t)(acc0[r] + bv);
            int row1 = row0 + 16;
            if (row1 < n) out[(size_t)row1 * H + col] = (bf16_t)(acc1[r] + bv);
        }
    }
}

// ---------------- GRU: column-tiled, LDS-persistent weights, barrier-free row loop ----
// grid = 4 * GRU_RB; cg = bid&3 owns cols [cg*32, cg*32+32); weights staged ONCE.
template<bool LOGITS>
__global__ __launch_bounds__(256) void gru_kernel(
    const bf16_t* __restrict__ inp, const bf16_t* __restrict__ hidb,
    const bf16_t* __restrict__ Wih, const bf16_t* __restrict__ Whh,
    const float* __restrict__ bih, const float* __restrict__ bhh,
    bf16_t* __restrict__ out, const float* __restrict__ Wo,
    float* __restrict__ pl, int n) {
    __shared__ __align__(16) unsigned char wlds[12 * 4096];
    int tid = threadIdx.x;
    int wid = tid >> 6, lane = tid & 63;
    int cg = blockIdx.x & 3;
    int rb = blockIdx.x >> 2;
    int rstride = gridDim.x >> 2;
    int lrow = lane & 15, lq = lane >> 4, lk8 = lq * 8;

    // ---- stage 12 slabs (2 col-halves x {ir,iz,in,hr,hz,hn}) once ----
    int srow = tid >> 4, sseg = tid & 15;
    int s_src = srow * 128 + sseg * 8;
    int s_lds = srow * 256 + ((sseg * 16) ^ ((srow & 7) << 4));
    #pragma unroll
    for (int p = 0; p < 2; ++p) {
        #pragma unroll
        for (int s = 0; s < 3; ++s) {
            *(uint4*)(&wlds[(p * 6 + s) * 4096 + s_lds]) =
                *(const uint4*)(Wih + (size_t)(s * 128 + cg * 32 + p * 16) * 128 + s_src);
            *(uint4*)(&wlds[(p * 6 + 3 + s) * 4096 + s_lds]) =
                *(const uint4*)(Whh + (size_t)(s * 128 + cg * 32 + p * 16) * 128 + s_src);
        }
    }
    __syncthreads();

    // per-lane constants for this block's 32 cols
    int colA = cg * 32 + lrow, colB = colA + 16;
    float birA = bih[colA], bizA = bih[128 + colA], binA = bih[256 + colA];
    float bhrA = bhh[colA], bhzA = bhh[128 + colA], bhnA = bhh[256 + colA];
    float birB = bih[colB], bizB = bih[128 + colB], binB = bih[256 + colB];
    float bhrB = bhh[colB], bhzB = bhh[128 + colB], bhnB = bhh[256 + colB];
    float w0A = 0.f, w1A = 0.f, w0B = 0.f, w1B = 0.f;
    if (LOGITS) {
        float2 wa = *(const float2*)(Wo + colA * 2); w0A = wa.x; w1A = wa.y;
        float2 wb = *(const float2*)(Wo + colB * 2); w0B = wb.x; w1B = wb.y;
    }

    int nrt = (n + 127) >> 7;
    for (int rbi = rb; rbi < nrt; rbi += rstride) {
        int r0 = rbi * 128 + wid * 32;
        bf16x8 ai[2][4], ah[2][4];
        for (int rt = 0; rt < 2; ++rt) {
            int row = r0 + rt * 16 + lrow;
            if (row >= n) row = n - 1;
            #pragma unroll
            for (int t = 0; t < 4; ++t) {
                ai[rt][t] = *(const bf16x8*)(inp  + (size_t)row * H + t * 32 + lk8);
                ah[rt][t] = *(const bf16x8*)(hidb + (size_t)row * H + t * 32 + lk8);
            }
        }
        float s0[2][4], s1[2][4];
        if (LOGITS) {
            #pragma unroll
            for (int rt = 0; rt < 2; ++rt)
                #pragma unroll
                for (int r = 0; r < 4; ++r) { s0[rt][r] = 0.f; s1[rt][r] = 0.f; }
        }

        #pragma unroll
        for (int p = 0; p < 2; ++p) {
            int ctg = cg * 2 + p;
            int col = ctg * 16 + lrow;
            f32x4 air[2], aiz[2], ain[2], ahr[2], ahz[2], ahn[2];
            #pragma unroll
            for (int rt = 0; rt < 2; ++rt) {
                air[rt] = (f32x4){0.f,0.f,0.f,0.f}; aiz[rt] = (f32x4){0.f,0.f,0.f,0.f};
                ain[rt] = (f32x4){0.f,0.f,0.f,0.f}; ahr[rt] = (f32x4){0.f,0.f,0.f,0.f};
                ahz[rt] = (f32x4){0.f,0.f,0.f,0.f}; ahn[rt] = (f32x4){0.f,0.f,0.f,0.f};
            }
            int rbase = lrow * 256;
            int sw = (lrow & 7) << 4;
            const unsigned char* wb_ = &wlds[p * 6 * 4096];
            #pragma unroll
            for (int t = 0; t < 4; ++t) {
                int roff = rbase + ((t * 64 + lq * 16) ^ sw);
                bf16x8 bir = *(const bf16x8*)(wb_ + 0 * 4096 + roff);
                bf16x8 biz = *(const bf16x8*)(wb_ + 1 * 4096 + roff);
                bf16x8 bin = *(const bf16x8*)(wb_ + 2 * 4096 + roff);
                bf16x8 bhr = *(const bf16x8*)(wb_ + 3 * 4096 + roff);
                bf16x8 bhz = *(const bf16x8*)(wb_ + 4 * 4096 + roff);
                bf16x8 bhn = *(const bf16x8*)(wb_ + 5 * 4096 + roff);
                #pragma unroll
                for (int rt = 0; rt < 2; ++rt) {
                    air[rt] = __builtin_amdgcn_mfma_f32_16x16x32_bf16(ai[rt][t], bir, air[rt], 0, 0, 0);
                    aiz[rt] = __builtin_amdgcn_mfma_f32_16x16x32_bf16(ai[rt][t], biz, aiz[rt], 0, 0, 0);
                    ain[rt] = __builtin_amdgcn_mfma_f32_16x16x32_bf16(ai[rt][t], bin, ain[rt], 0, 0, 0);
                    ahr[rt] = __builtin_amdgcn_mfma_f32_16x16x32_bf16(ah[rt][t], bhr, ahr[rt], 0, 0, 0);
                    ahz[rt] = __builtin_amdgcn_mfma_f32_16x16x32_bf16(ah[rt][t], bhz, ahz[rt], 0, 0, 0);
                    ahn[rt] = __builtin_amdgcn_mfma_f32_16x16x32_bf16(ah[rt][t], bhn, ahn[rt], 0, 0, 0);
                }
            }

            // hid at C-layout via identity-MFMA (exact x1.0)
            int idx = ((ctg & 1) << 4) | lrow;
            bf16x8 bid;
            #pragma unroll
            for (int j = 0; j < 8; ++j)
                bid[j] = (bf16_t)((lq == (idx >> 3) && j == (idx & 7)) ? 1.f : 0.f);
            int tct = ctg >> 1;
            f32x4 zz = {0.f, 0.f, 0.f, 0.f};
            f32x4 hc0 = __builtin_amdgcn_mfma_f32_16x16x32_bf16(ah[0][tct], bid, zz, 0, 0, 0);
            f32x4 hc1 = __builtin_amdgcn_mfma_f32_16x16x32_bf16(ah[1][tct], bid, zz, 0, 0, 0);

            float b_ir = p ? birB : birA, b_iz = p ? bizB : bizA, b_in = p ? binB : binA;
            float b_hr = p ? bhrB : bhrA, b_hz = p ? bhzB : bhzA, b_hn = p ? bhnB : bhnA;
            float w0 = p ? w0B : w0A, w1 = p ? w1B : w1A;
            #pragma unroll
            for (int rt = 0; rt < 2; ++rt) {
                #pragma unroll
                for (int r = 0; r < 4; ++r) {
                    int row = r0 + rt * 16 + lq * 4 + r;
                    float irv = air[rt][r] + b_ir, hrv = ahr[rt][r] + b_hr;
                    float izv = aiz[rt][r] + b_iz, hzv = ahz[rt][r] + b_hz;
                    float inv = ain[rt][r] + b_in, hnv = ahn[rt][r] + b_hn;
                    float rg = 1.f / (1.f + __expf(-(irv + hrv)));
                    float zg = 1.f / (1.f + __expf(-(izv + hzv)));
                    float xx = inv + rg * hnv;
                    float ng = 2.f / (1.f + __expf(-2.f * xx)) - 1.f;   // tanh
                    float hv = rt ? hc1[r] : hc0[r];
                    float hout = (1.f - zg) * ng + zg * hv;
                    if (LOGITS) {
                        s0[rt][r] += hout * w0;
                        s1[rt][r] += hout * w1;
                    } else if (row < n) {
                        out[(size_t)row * H + col] = (bf16_t)hout;
                    }
                }
            }
        }

        if (LOGITS) {
            #pragma unroll
            for (int m = 1; m < 16; m <<= 1) {
                #pragma unroll
                for (int rt = 0; rt < 2; ++rt)
                    #pragma unroll
                    for (int r = 0; r < 4; ++r) {
                        s0[rt][r] += __shfl_xor(s0[rt][r], m);
                        s1[rt][r] += __shfl_xor(s1[rt][r], m);
                    }
            }
            if (lrow == 0) {
                #pragma unroll
                for (int rt = 0; rt < 2; ++rt)
                    #pragma unroll
                    for (int r = 0; r < 4; ++r) {
                        int row = r0 + rt * 16 + lq * 4 + r;
                        if (row < n) {
                            pl[(size_t)row * 8 + cg * 2]     = s0[rt][r];
                            pl[(size_t)row * 8 + cg * 2 + 1] = s1[rt][r];
                        }
                    }
            }
        }
    }
}

// ---------------- finalize: sum col-group partials, bias, log_softmax ----------------
__global__ void head_finalize(const float* __restrict__ pl, const float* __restrict__ bo,
                              float* __restrict__ outp, int n) {
    int row = blockIdx.x * blockDim.x + threadIdx.x;
    if (row >= n) return;
    const float4* p = (const float4*)(pl + (size_t)row * 8);
    float4 a = p[0], b = p[1];
    float l0 = a.x + a.z + b.x + b.z + bo[0];
    float l1 = a.y + a.w + b.y + b.w + bo[1];
    float mx = fmaxf(l0, l1);
    float lse = mx + __logf(__expf(l0 - mx) + __expf(l1 - mx));
    outp[(size_t)row * 2]     = l0 - lse;
    outp[(size_t)row * 2 + 1] = l1 - lse;
}

extern "C" void kernel_launch(void* const* d_in, const int* in_sizes, int n_in,
                              void* d_out, int out_size, void* d_ws, size_t ws_size,
                              hipStream_t stream) {
    const float* x   = (const float*)d_in[0];
    const int*   ei  = (const int*)d_in[1];
    const float* ew  = (const float*)d_in[2];
    const float* Wf  = (const float*)d_in[3];
    const float* bf  = (const float*)d_in[4];
    const float* Wih = (const float*)d_in[5];
    const float* bih = (const float*)d_in[6];
    const float* Whh = (const float*)d_in[7];
    const float* bhh = (const float*)d_in[8];
    const float* Wl1 = (const float*)d_in[9];
    const float* bl1 = (const float*)d_in[10];
    const float* Wo  = (const float*)d_in[11];
    const float* bo  = (const float*)d_in[12];

    int n  = in_sizes[0] / H;     // 100000
    int nE = in_sizes[2];         // 1600000

    bf16_t* hbufb = (bf16_t*)d_ws;                        // [n][H] hidden
    bf16_t* b1b   = hbufb + (size_t)n * H;                // [n][H] conv1 out / conv2 out
    bf16_t* b2b   = b1b + (size_t)n * H;                  // [n][H] lin1 out
    bf16_t* b3b   = b2b + (size_t)n * H;                  // [n][H] gru1 out
    float*  pl    = (float*)(b3b + (size_t)n * H);        // [n][8] logit partials
    bf16_t* wfT   = (bf16_t*)(pl + (size_t)n * 8);
    bf16_t* wih   = wfT + 128 * 128;
    bf16_t* whh   = wih + 384 * 128;
    bf16_t* wl1T  = whh + 384 * 128;
    int* deg    = (int*)(wl1T + 128 * 128);               // [n]
    int* rowptr = deg + n;                                // [n+1]
    int* cursor = rowptr + (n + 1);                       // [n]
    int2* srcw  = (int2*)((char*)(cursor + n) + ((size_t)(-(intptr_t)(cursor + n)) & 7)); // [nE]

    int gemmGrid = (n + 127) / 128;
    int nScanBlocks = (n + SCAN_CHUNK - 1) / SCAN_CHUNK;

    // ---- weights + CSR build ----
    prep_weights<<<192, 256, 0, stream>>>(Wf, Wih, Whh, Wl1, wfT, wih, whh, wl1T);
    hipMemsetAsync(deg, 0, (size_t)n * sizeof(int), stream);
    hist_kernel<<<(nE + 255) / 256, 256, 0, stream>>>(ei, deg, nE);
    scan1_kernel<<<nScanBlocks, SCAN_T, 0, stream>>>(deg, rowptr, cursor, n);
    scan2_kernel<<<1, SCAN_T, 0, stream>>>(cursor, nScanBlocks);
    scan3_kernel<<<(n + 255) / 256, 256, 0, stream>>>(rowptr, deg, cursor, n, nE);
    scatter_kernel<<<2048, 256, 0, stream>>>(ei, ew, deg, srcw, nE, n);

    // ---- pipeline ----
    lin_first_kernel<<<gemmGrid, 256, 0, stream>>>(x, wfT, bf, hbufb, n);
    conv_csr_kernel<<<(n + 3) / 4, 256, 0, stream>>>(hbufb, rowptr, srcw, b1b, n);
    gru_kernel<false><<<4 * GRU_RB, 256, 0, stream>>>(b1b, hbufb, wih, whh, bih, bhh,
                                                      b3b, nullptr, nullptr, n);
    lin_mid_kernel<<<gemmGrid, 256, 0, stream>>>(b3b, wl1T, bl1, b2b, n);
    conv_csr_kernel<<<(n + 3) / 4, 256, 0, stream>>>(b2b, rowptr, srcw, b1b, n);
    gru_kernel<true><<<4 * GRU_RB, 256, 0, stream>>>(b1b, hbufb, wih, whh, bih, bhh,
                                                     nullptr, Wo, pl, n);
    head_finalize<<<(n + 255) / 256, 256, 0, stream>>>(pl, bo, (float*)d_out, n);
}

// Round 8
// 583.875 us; speedup vs baseline: 1.2599x; 1.1384x over previous
//
#include <hip/hip_runtime.h>
#include <hip/hip_bf16.h>

#define H 128
#define SCAN_T 256
#define SCAN_I 8
#define SCAN_CHUNK (SCAN_T * SCAN_I)   // 2048 elems per scan block

typedef __bf16 bf16_t;
typedef __attribute__((ext_vector_type(2))) __bf16 bf16x2;
typedef __attribute__((ext_vector_type(8))) __bf16 bf16x8;
typedef __attribute__((ext_vector_type(4))) float f32x4;

static_assert(sizeof(bf16x8) == 16, "bf16x8 must be 16 bytes");

// f32 source -> A-fragment (8 bf16) for mfma_f32_16x16x32_bf16
__device__ inline bf16x8 load_a_frag_f32(const float* __restrict__ A, int row, int koff) {
    const float4* p = (const float4*)(A + (size_t)row * H + koff);
    float4 v0 = p[0], v1 = p[1];
    bf16x8 r;
    r[0] = (bf16_t)v0.x; r[1] = (bf16_t)v0.y; r[2] = (bf16_t)v0.z; r[3] = (bf16_t)v0.w;
    r[4] = (bf16_t)v1.x; r[5] = (bf16_t)v1.y; r[6] = (bf16_t)v1.z; r[7] = (bf16_t)v1.w;
    return r;
}

// ---------------- weight prep ----------------
__global__ void prep_weights(const float* __restrict__ Wf,  const float* __restrict__ Wih,
                             const float* __restrict__ Whh, const float* __restrict__ Wl1,
                             bf16_t* __restrict__ wfT, bf16_t* __restrict__ wih,
                             bf16_t* __restrict__ whh, bf16_t* __restrict__ wl1T) {
    int i = blockIdx.x * blockDim.x + threadIdx.x;
    if (i < 128 * 128) {
        int c = i >> 7, k = i & 127;
        wfT[i]  = (bf16_t)Wf[k * 128 + c];   // [k][c] -> [c][k]
        wl1T[i] = (bf16_t)Wl1[k * 128 + c];
    }
    if (i < 384 * 128) {
        wih[i] = (bf16_t)Wih[i];
        whh[i] = (bf16_t)Whh[i];
    }
}

// ---------------- CSR build ----------------
__global__ void hist_kernel(const int* __restrict__ ei, int* __restrict__ deg, int nE) {
    int e = blockIdx.x * blockDim.x + threadIdx.x;
    if (e < nE) atomicAdd(&deg[ei[nE + e]], 1);
}

__global__ __launch_bounds__(SCAN_T) void scan1_kernel(
    const int* __restrict__ deg, int* __restrict__ rowptr, int* __restrict__ bsum, int n) {
    __shared__ int s[SCAN_T];
    int base = blockIdx.x * SCAN_CHUNK + threadIdx.x * SCAN_I;
    int v[SCAN_I];
    int sum = 0;
    for (int j = 0; j < SCAN_I; ++j) {
        int idx = base + j;
        v[j] = (idx < n) ? deg[idx] : 0;
        sum += v[j];
    }
    s[threadIdx.x] = sum;
    __syncthreads();
    for (int off = 1; off < SCAN_T; off <<= 1) {
        int t = (threadIdx.x >= off) ? s[threadIdx.x - off] : 0;
        __syncthreads();
        s[threadIdx.x] += t;
        __syncthreads();
    }
    int run = s[threadIdx.x] - sum;
    for (int j = 0; j < SCAN_I; ++j) {
        int idx = base + j;
        if (idx < n) rowptr[idx] = run;
        run += v[j];
    }
    if (threadIdx.x == SCAN_T - 1) bsum[blockIdx.x] = s[SCAN_T - 1];
}

__global__ __launch_bounds__(SCAN_T) void scan2_kernel(int* __restrict__ bsum, int nb) {
    __shared__ int s[SCAN_T];
    int v = (threadIdx.x < nb) ? bsum[threadIdx.x] : 0;
    s[threadIdx.x] = v;
    __syncthreads();
    for (int off = 1; off < SCAN_T; off <<= 1) {
        int t = (threadIdx.x >= off) ? s[threadIdx.x - off] : 0;
        __syncthreads();
        s[threadIdx.x] += t;
        __syncthreads();
    }
    if (threadIdx.x < nb) bsum[threadIdx.x] = s[threadIdx.x] - v;
}

__global__ void scan3_kernel(int* __restrict__ rowptr, int* __restrict__ cursor,
                             const int* __restrict__ bsum, int n, int nE) {
    int idx = blockIdx.x * blockDim.x + threadIdx.x;
    if (idx < n) {
        int val = rowptr[idx] + bsum[idx / SCAN_CHUNK];
        rowptr[idx] = val;
        cursor[idx] = val;
    }
    if (idx == 0) rowptr[n] = nE;
}

// XCD-bucketed scatter: block r=bid&7 handles dst range [r*n/8, (r+1)*n/8).
__global__ __launch_bounds__(256) void scatter_kernel(
    const int* __restrict__ ei, const float* __restrict__ ew,
    int* __restrict__ cursor, int2* __restrict__ srcw, int nE, int n) {
    int r = blockIdx.x & 7;
    int nslice = n >> 3;
    int lo = r * nslice;
    int hi = (r == 7) ? n : lo + nslice;
    int chunk = blockIdx.x >> 3;
    int nchunk = gridDim.x >> 3;
    for (int e = chunk * 256 + threadIdx.x; e < nE; e += nchunk * 256) {
        int dst = ei[nE + e];
        if (dst >= lo && dst < hi) {
            int pos = atomicAdd(&cursor[dst], 1);
            srcw[pos] = make_int2(ei[e], __float_as_int(ew[e]));
        }
    }
}

// ---------------- gated conv via CSR: 4 edges in flight per wave ----------------
__device__ inline void conv_fma(float* acc, uint4 u, float w) {
    acc[0] += __uint_as_float(u.x << 16) * w;
    acc[1] += __uint_as_float(u.x & 0xffff0000u) * w;
    acc[2] += __uint_as_float(u.y << 16) * w;
    acc[3] += __uint_as_float(u.y & 0xffff0000u) * w;
    acc[4] += __uint_as_float(u.z << 16) * w;
    acc[5] += __uint_as_float(u.z & 0xffff0000u) * w;
    acc[6] += __uint_as_float(u.w << 16) * w;
    acc[7] += __uint_as_float(u.w & 0xffff0000u) * w;
}

__global__ __launch_bounds__(256) void conv_csr_kernel(
    const bf16_t* __restrict__ xb, const int* __restrict__ rowptr,
    const int2* __restrict__ srcw, bf16_t* __restrict__ agg, int n) {
    int lane = threadIdx.x & 63;
    int d = (blockIdx.x * blockDim.x + threadIdx.x) >> 6;
    if (d >= n) return;
    int q = lane >> 4;
    int l = lane & 15;
    int beg = rowptr[d], end = rowptr[d + 1];

    float acc[8];
    #pragma unroll
    for (int i = 0; i < 8; ++i) acc[i] = 0.f;

    int e = beg + q;
    for (; e + 4 < end; e += 8) {
        int2 sw0 = srcw[e];
        int2 sw1 = srcw[e + 4];
        uint4 u0 = *(const uint4*)(xb + (size_t)sw0.x * H + l * 8);
        uint4 u1 = *(const uint4*)(xb + (size_t)sw1.x * H + l * 8);
        conv_fma(acc, u0, __int_as_float(sw0.y));
        conv_fma(acc, u1, __int_as_float(sw1.y));
    }
    if (e < end) {
        int2 sw = srcw[e];
        uint4 u = *(const uint4*)(xb + (size_t)sw.x * H + l * 8);
        conv_fma(acc, u, __int_as_float(sw.y));
    }

    #pragma unroll
    for (int i = 0; i < 8; ++i) {
        acc[i] += __shfl_xor(acc[i], 16);
        acc[i] += __shfl_xor(acc[i], 32);
    }
    if (q == 0) {
        bf16x8 r;
        #pragma unroll
        for (int i = 0; i < 8; ++i) r[i] = (bf16_t)acc[i];
        *(bf16x8*)(agg + (size_t)d * H + l * 8) = r;
    }
}

// ---------------- lin kernels: whole 32KB weight staged in LDS (swizzled) ----------------
// 16B granule (row, seg) -> byte row*256 + ((seg*16) ^ ((row&7)<<4))

__global__ __launch_bounds__(256) void lin_first_kernel(
    const float* __restrict__ A, const bf16_t* __restrict__ Bt,
    const float* __restrict__ bias, bf16_t* __restrict__ outb, int n) {
    __shared__ __align__(16) unsigned char wlds[32768];
    int tid = threadIdx.x;
    int wid = tid >> 6, lane = tid & 63;
    int r0 = (blockIdx.x * 4 + wid) * 32;
    int lrow = lane & 15, lq = lane >> 4, lk8 = lq * 8;

    #pragma unroll
    for (int i = 0; i < 8; ++i) {
        int g = i * 256 + tid;
        int row = g >> 4, seg = g & 15;
        uint4 v = *(const uint4*)(Bt + row * 128 + seg * 8);
        *(uint4*)(&wlds[row * 256 + ((seg * 16) ^ ((row & 7) << 4))]) = v;
    }

    bf16x8 a[2][4];
    for (int rt = 0; rt < 2; ++rt) {
        int row = r0 + rt * 16 + lrow;
        if (row >= n) row = n - 1;
        for (int t = 0; t < 4; ++t) a[rt][t] = load_a_frag_f32(A, row, t * 32 + lk8);
    }
    __syncthreads();

    for (int ct = 0; ct < 8; ++ct) {
        int c0 = ct * 16;
        f32x4 acc0 = {0.f, 0.f, 0.f, 0.f}, acc1 = {0.f, 0.f, 0.f, 0.f};
        int rbase = (c0 + lrow) * 256;
        int sw = (lrow & 7) << 4;
        #pragma unroll
        for (int t = 0; t < 4; ++t) {
            bf16x8 b = *(const bf16x8*)(&wlds[rbase + ((t * 64 + lq * 16) ^ sw)]);
            acc0 = __builtin_amdgcn_mfma_f32_16x16x32_bf16(a[0][t], b, acc0, 0, 0, 0);
            acc1 = __builtin_amdgcn_mfma_f32_16x16x32_bf16(a[1][t], b, acc1, 0, 0, 0);
        }
        int col = c0 + lrow;
        float bv = bias[col];
        for (int r = 0; r < 4; ++r) {
            int row0 = r0 + lq * 4 + r;
            if (row0 < n) outb[(size_t)row0 * H + col] = (bf16_t)(acc0[r] + bv);
            int row1 = row0 + 16;
            if (row1 < n) outb[(size_t)row1 * H + col] = (bf16_t)(acc1[r] + bv);
        }
    }
}

__global__ __launch_bounds__(256) void lin_mid_kernel(
    const bf16_t* __restrict__ A, const bf16_t* __restrict__ Bt,
    const float* __restrict__ bias, bf16_t* __restrict__ out, int n) {
    __shared__ __align__(16) unsigned char wlds[32768];
    int tid = threadIdx.x;
    int wid = tid >> 6, lane = tid & 63;
    int r0 = (blockIdx.x * 4 + wid) * 32;
    int lrow = lane & 15, lq = lane >> 4, lk8 = lq * 8;

    #pragma unroll
    for (int i = 0; i < 8; ++i) {
        int g = i * 256 + tid;
        int row = g >> 4, seg = g & 15;
        uint4 v = *(const uint4*)(Bt + row * 128 + seg * 8);
        *(uint4*)(&wlds[row * 256 + ((seg * 16) ^ ((row & 7) << 4))]) = v;
    }

    bf16x8 a[2][4];
    for (int rt = 0; rt < 2; ++rt) {
        int row = r0 + rt * 16 + lrow;
        if (row >= n) row = n - 1;
        for (int t = 0; t < 4; ++t)
            a[rt][t] = *(const bf16x8*)(A + (size_t)row * H + t * 32 + lk8);
    }
    __syncthreads();

    for (int ct = 0; ct < 8; ++ct) {
        int c0 = ct * 16;
        f32x4 acc0 = {0.f, 0.f, 0.f, 0.f}, acc1 = {0.f, 0.f, 0.f, 0.f};
        int rbase = (c0 + lrow) * 256;
        int sw = (lrow & 7) << 4;
        #pragma unroll
        for (int t = 0; t < 4; ++t) {
            bf16x8 b = *(const bf16x8*)(&wlds[rbase + ((t * 64 + lq * 16) ^ sw)]);
            acc0 = __builtin_amdgcn_mfma_f32_16x16x32_bf16(a[0][t], b, acc0, 0, 0, 0);
            acc1 = __builtin_amdgcn_mfma_f32_16x16x32_bf16(a[1][t], b, acc1, 0, 0, 0);
        }
        int col = c0 + lrow;
        float bv = bias[col];
        for (int r = 0; r < 4; ++r) {
            int row0 = r0 + lq * 4 + r;
            if (row0 < n) out[(size_t)row0 * H + col] = (bf16_t)(acc0[r] + bv);
            int row1 = row0 + 16;
            if (row1 < n) out[(size_t)row1 * H + col] = (bf16_t)(acc1[r] + bv);
        }
    }
}

// ---------------- GRU: column-tiled, LDS-persistent weights, 16-row waves ----------------
// grid = 4 * RB; cg = bid&3 owns cols [cg*32, cg*32+32); weights staged ONCE.
// Each wave: 16 rows/iter -> ai/ah = 32 VGPR, 6 live accumulators (24 VGPR).
template<bool LOGITS>
__global__ __launch_bounds__(256) void gru_kernel(
    const bf16_t* __restrict__ inp, const bf16_t* __restrict__ hidb,
    const bf16_t* __restrict__ Wih, const bf16_t* __restrict__ Whh,
    const float* __restrict__ bih, const float* __restrict__ bhh,
    bf16_t* __restrict__ out, const float* __restrict__ Wo,
    float* __restrict__ pl, int n) {
    __shared__ __align__(16) unsigned char wlds[12 * 4096];
    int tid = threadIdx.x;
    int wid = tid >> 6, lane = tid & 63;
    int cg = blockIdx.x & 3;
    int rb = blockIdx.x >> 2;
    int rstride = gridDim.x >> 2;
    int lrow = lane & 15, lq = lane >> 4, lk8 = lq * 8;

    // ---- stage 12 slabs (2 col-halves x {ir,iz,in,hr,hz,hn}) once ----
    int srow = tid >> 4, sseg = tid & 15;
    int s_src = srow * 128 + sseg * 8;
    int s_lds = srow * 256 + ((sseg * 16) ^ ((srow & 7) << 4));
    #pragma unroll
    for (int p = 0; p < 2; ++p) {
        #pragma unroll
        for (int s = 0; s < 3; ++s) {
            *(uint4*)(&wlds[(p * 6 + s) * 4096 + s_lds]) =
                *(const uint4*)(Wih + (size_t)(s * 128 + cg * 32 + p * 16) * 128 + s_src);
            *(uint4*)(&wlds[(p * 6 + 3 + s) * 4096 + s_lds]) =
                *(const uint4*)(Whh + (size_t)(s * 128 + cg * 32 + p * 16) * 128 + s_src);
        }
    }
    __syncthreads();

    // per-lane constants (loop-invariant)
    int colA = cg * 32 + lrow, colB = colA + 16;
    float birA = bih[colA], bizA = bih[128 + colA], binA = bih[256 + colA];
    float bhrA = bhh[colA], bhzA = bhh[128 + colA], bhnA = bhh[256 + colA];
    float birB = bih[colB], bizB = bih[128 + colB], binB = bih[256 + colB];
    float bhrB = bhh[colB], bhzB = bhh[128 + colB], bhnB = bhh[256 + colB];
    float w0A = 0.f, w1A = 0.f, w0B = 0.f, w1B = 0.f;
    if (LOGITS) {
        float2 wa = *(const float2*)(Wo + colA * 2); w0A = wa.x; w1A = wa.y;
        float2 wb = *(const float2*)(Wo + colB * 2); w0B = wb.x; w1B = wb.y;
    }
    // hoisted identity B-fragments (tct = cg, idx = p*16 + lrow)
    bf16x8 bidA, bidB;
    #pragma unroll
    for (int j = 0; j < 8; ++j) {
        bidA[j] = (bf16_t)((lq == (lrow >> 3) && j == (lrow & 7)) ? 1.f : 0.f);
        int ix = 16 + lrow;
        bidB[j] = (bf16_t)((lq == (ix >> 3) && j == (ix & 7)) ? 1.f : 0.f);
    }
    int rbase = lrow * 256;
    int swz = (lrow & 7) << 4;

    int nrt = (n + 63) >> 6;
    for (int rbi = rb; rbi < nrt; rbi += rstride) {
        int r0 = rbi * 64 + wid * 16;
        int rowl = r0 + lrow;
        if (rowl >= n) rowl = n - 1;
        bf16x8 ai[4], ah[4];
        #pragma unroll
        for (int t = 0; t < 4; ++t) {
            ai[t] = *(const bf16x8*)(inp  + (size_t)rowl * H + t * 32 + lk8);
            ah[t] = *(const bf16x8*)(hidb + (size_t)rowl * H + t * 32 + lk8);
        }
        float s0[4], s1[4];
        if (LOGITS) {
            #pragma unroll
            for (int r = 0; r < 4; ++r) { s0[r] = 0.f; s1[r] = 0.f; }
        }

        #pragma unroll
        for (int p = 0; p < 2; ++p) {
            f32x4 air = {0.f,0.f,0.f,0.f}, aiz = {0.f,0.f,0.f,0.f}, ain = {0.f,0.f,0.f,0.f};
            f32x4 ahr = {0.f,0.f,0.f,0.f}, ahz = {0.f,0.f,0.f,0.f}, ahn = {0.f,0.f,0.f,0.f};
            const unsigned char* wb_ = &wlds[p * 6 * 4096];
            #pragma unroll
            for (int t = 0; t < 4; ++t) {
                int roff = rbase + ((t * 64 + lq * 16) ^ swz);
                bf16x8 bir = *(const bf16x8*)(wb_ + 0 * 4096 + roff);
                bf16x8 biz = *(const bf16x8*)(wb_ + 1 * 4096 + roff);
                bf16x8 bin = *(const bf16x8*)(wb_ + 2 * 4096 + roff);
                bf16x8 bhr = *(const bf16x8*)(wb_ + 3 * 4096 + roff);
                bf16x8 bhz = *(const bf16x8*)(wb_ + 4 * 4096 + roff);
                bf16x8 bhn = *(const bf16x8*)(wb_ + 5 * 4096 + roff);
                air = __builtin_amdgcn_mfma_f32_16x16x32_bf16(ai[t], bir, air, 0, 0, 0);
                aiz = __builtin_amdgcn_mfma_f32_16x16x32_bf16(ai[t], biz, aiz, 0, 0, 0);
                ain = __builtin_amdgcn_mfma_f32_16x16x32_bf16(ai[t], bin, ain, 0, 0, 0);
                ahr = __builtin_amdgcn_mfma_f32_16x16x32_bf16(ah[t], bhr, ahr, 0, 0, 0);
                ahz = __builtin_amdgcn_mfma_f32_16x16x32_bf16(ah[t], bhz, ahz, 0, 0, 0);
                ahn = __builtin_amdgcn_mfma_f32_16x16x32_bf16(ah[t], bhn, ahn, 0, 0, 0);
            }
            f32x4 zz = {0.f, 0.f, 0.f, 0.f};
            f32x4 hc = __builtin_amdgcn_mfma_f32_16x16x32_bf16(ah[cg], p ? bidB : bidA, zz, 0, 0, 0);

            float b_ir = p ? birB : birA, b_iz = p ? bizB : bizA, b_in = p ? binB : binA;
            float b_hr = p ? bhrB : bhrA, b_hz = p ? bhzB : bhzA, b_hn = p ? bhnB : bhnA;
            float w0 = p ? w0B : w0A, w1 = p ? w1B : w1A;
            int col = cg * 32 + p * 16 + lrow;
            #pragma unroll
            for (int r = 0; r < 4; ++r) {
                int row = r0 + lq * 4 + r;
                float irv = air[r] + b_ir, hrv = ahr[r] + b_hr;
                float izv = aiz[r] + b_iz, hzv = ahz[r] + b_hz;
                float inv = ain[r] + b_in, hnv = ahn[r] + b_hn;
                float rg = 1.f / (1.f + __expf(-(irv + hrv)));
                float zg = 1.f / (1.f + __expf(-(izv + hzv)));
                float xx = inv + rg * hnv;
                float ng = 2.f / (1.f + __expf(-2.f * xx)) - 1.f;   // tanh
                float hout = (1.f - zg) * ng + zg * hc[r];
                if (LOGITS) {
                    s0[r] += hout * w0;
                    s1[r] += hout * w1;
                } else if (row < n) {
                    out[(size_t)row * H + col] = (bf16_t)hout;
                }
            }
        }

        if (LOGITS) {
            #pragma unroll
            for (int m = 1; m < 16; m <<= 1) {
                #pragma unroll
                for (int r = 0; r < 4; ++r) {
                    s0[r] += __shfl_xor(s0[r], m);
                    s1[r] += __shfl_xor(s1[r], m);
                }
            }
            if (lrow == 0) {
                #pragma unroll
                for (int r = 0; r < 4; ++r) {
                    int row = r0 + lq * 4 + r;
                    if (row < n) {
                        pl[(size_t)row * 8 + cg * 2]     = s0[r];
                        pl[(size_t)row * 8 + cg * 2 + 1] = s1[r];
                    }
                }
            }
        }
    }
}

// ---------------- finalize: sum col-group partials, bias, log_softmax ----------------
__global__ void head_finalize(const float* __restrict__ pl, const float* __restrict__ bo,
                              float* __restrict__ outp, int n) {
    int row = blockIdx.x * blockDim.x + threadIdx.x;
    if (row >= n) return;
    const float4* p = (const float4*)(pl + (size_t)row * 8);
    float4 a = p[0], b = p[1];
    float l0 = a.x + a.z + b.x + b.z + bo[0];
    float l1 = a.y + a.w + b.y + b.w + bo[1];
    float mx = fmaxf(l0, l1);
    float lse = mx + __logf(__expf(l0 - mx) + __expf(l1 - mx));
    outp[(size_t)row * 2]     = l0 - lse;
    outp[(size_t)row * 2 + 1] = l1 - lse;
}

extern "C" void kernel_launch(void* const* d_in, const int* in_sizes, int n_in,
                              void* d_out, int out_size, void* d_ws, size_t ws_size,
                              hipStream_t stream) {
    const float* x   = (const float*)d_in[0];
    const int*   ei  = (const int*)d_in[1];
    const float* ew  = (const float*)d_in[2];
    const float* Wf  = (const float*)d_in[3];
    const float* bf  = (const float*)d_in[4];
    const float* Wih = (const float*)d_in[5];
    const float* bih = (const float*)d_in[6];
    const float* Whh = (const float*)d_in[7];
    const float* bhh = (const float*)d_in[8];
    const float* Wl1 = (const float*)d_in[9];
    const float* bl1 = (const float*)d_in[10];
    const float* Wo  = (const float*)d_in[11];
    const float* bo  = (const float*)d_in[12];

    int n  = in_sizes[0] / H;     // 100000
    int nE = in_sizes[2];         // 1600000

    bf16_t* hbufb = (bf16_t*)d_ws;                        // [n][H] hidden
    bf16_t* b1b   = hbufb + (size_t)n * H;                // [n][H] conv1 out / conv2 out
    bf16_t* b2b   = b1b + (size_t)n * H;                  // [n][H] lin1 out
    bf16_t* b3b   = b2b + (size_t)n * H;                  // [n][H] gru1 out
    float*  pl    = (float*)(b3b + (size_t)n * H);        // [n][8] logit partials
    bf16_t* wfT   = (bf16_t*)(pl + (size_t)n * 8);
    bf16_t* wih   = wfT + 128 * 128;
    bf16_t* whh   = wih + 384 * 128;
    bf16_t* wl1T  = whh + 384 * 128;
    int* deg    = (int*)(wl1T + 128 * 128);               // [n]
    int* rowptr = deg + n;                                // [n+1]
    int* cursor = rowptr + (n + 1);                       // [n]
    int2* srcw  = (int2*)((char*)(cursor + n) + ((size_t)(-(intptr_t)(cursor + n)) & 7)); // [nE]

    int gemmGrid = (n + 127) / 128;
    int nScanBlocks = (n + SCAN_CHUNK - 1) / SCAN_CHUNK;

    // ---- weights + CSR build ----
    prep_weights<<<192, 256, 0, stream>>>(Wf, Wih, Whh, Wl1, wfT, wih, whh, wl1T);
    hipMemsetAsync(deg, 0, (size_t)n * sizeof(int), stream);
    hist_kernel<<<(nE + 255) / 256, 256, 0, stream>>>(ei, deg, nE);
    scan1_kernel<<<nScanBlocks, SCAN_T, 0, stream>>>(deg, rowptr, cursor, n);
    scan2_kernel<<<1, SCAN_T, 0, stream>>>(cursor, nScanBlocks);
    scan3_kernel<<<(n + 255) / 256, 256, 0, stream>>>(rowptr, deg, cursor, n, nE);
    scatter_kernel<<<2048, 256, 0, stream>>>(ei, ew, deg, srcw, nE, n);

    // ---- pipeline ----
    lin_first_kernel<<<gemmGrid, 256, 0, stream>>>(x, wfT, bf, hbufb, n);
    conv_csr_kernel<<<(n + 3) / 4, 256, 0, stream>>>(hbufb, rowptr, srcw, b1b, n);
    gru_kernel<false><<<2048, 256, 0, stream>>>(b1b, hbufb, wih, whh, bih, bhh,
                                                b3b, nullptr, nullptr, n);
    lin_mid_kernel<<<gemmGrid, 256, 0, stream>>>(b3b, wl1T, bl1, b2b, n);
    conv_csr_kernel<<<(n + 3) / 4, 256, 0, stream>>>(b2b, rowptr, srcw, b1b, n);
    gru_kernel<true><<<2048, 256, 0, stream>>>(b1b, hbufb, wih, whh, bih, bhh,
                                               nullptr, Wo, pl, n);
    head_finalize<<<(n + 255) / 256, 256, 0, stream>>>(pl, bo, (float*)d_out, n);
}

// Round 9
// 549.830 us; speedup vs baseline: 1.3379x; 1.0619x over previous
//
#include <hip/hip_runtime.h>
#include <hip/hip_bf16.h>

#define H 128
#define SCAN_T 256
#define SCAN_I 8
#define SCAN_CHUNK (SCAN_T * SCAN_I)   // 2048 elems per scan block

typedef __bf16 bf16_t;
typedef __attribute__((ext_vector_type(2))) __bf16 bf16x2;
typedef __attribute__((ext_vector_type(8))) __bf16 bf16x8;
typedef __attribute__((ext_vector_type(4))) float f32x4;

static_assert(sizeof(bf16x8) == 16, "bf16x8 must be 16 bytes");

// f32 source -> A-fragment (8 bf16) for mfma_f32_16x16x32_bf16
__device__ inline bf16x8 load_a_frag_f32(const float* __restrict__ A, int row, int koff) {
    const float4* p = (const float4*)(A + (size_t)row * H + koff);
    float4 v0 = p[0], v1 = p[1];
    bf16x8 r;
    r[0] = (bf16_t)v0.x; r[1] = (bf16_t)v0.y; r[2] = (bf16_t)v0.z; r[3] = (bf16_t)v0.w;
    r[4] = (bf16_t)v1.x; r[5] = (bf16_t)v1.y; r[6] = (bf16_t)v1.z; r[7] = (bf16_t)v1.w;
    return r;
}

// ---------------- weight prep ----------------
__global__ void prep_weights(const float* __restrict__ Wf,  const float* __restrict__ Wih,
                             const float* __restrict__ Whh, const float* __restrict__ Wl1,
                             bf16_t* __restrict__ wfT, bf16_t* __restrict__ wih,
                             bf16_t* __restrict__ whh, bf16_t* __restrict__ wl1T) {
    int i = blockIdx.x * blockDim.x + threadIdx.x;
    if (i < 128 * 128) {
        int c = i >> 7, k = i & 127;
        wfT[i]  = (bf16_t)Wf[k * 128 + c];   // [k][c] -> [c][k]
        wl1T[i] = (bf16_t)Wl1[k * 128 + c];
    }
    if (i < 384 * 128) {
        wih[i] = (bf16_t)Wih[i];
        whh[i] = (bf16_t)Whh[i];
    }
}

// ---------------- CSR build ----------------
__global__ void hist_kernel(const int* __restrict__ ei, int* __restrict__ deg, int nE) {
    int e = blockIdx.x * blockDim.x + threadIdx.x;
    if (e < nE) atomicAdd(&deg[ei[nE + e]], 1);
}

__global__ __launch_bounds__(SCAN_T) void scan1_kernel(
    const int* __restrict__ deg, int* __restrict__ rowptr, int* __restrict__ bsum, int n) {
    __shared__ int s[SCAN_T];
    int base = blockIdx.x * SCAN_CHUNK + threadIdx.x * SCAN_I;
    int v[SCAN_I];
    int sum = 0;
    for (int j = 0; j < SCAN_I; ++j) {
        int idx = base + j;
        v[j] = (idx < n) ? deg[idx] : 0;
        sum += v[j];
    }
    s[threadIdx.x] = sum;
    __syncthreads();
    for (int off = 1; off < SCAN_T; off <<= 1) {
        int t = (threadIdx.x >= off) ? s[threadIdx.x - off] : 0;
        __syncthreads();
        s[threadIdx.x] += t;
        __syncthreads();
    }
    int run = s[threadIdx.x] - sum;
    for (int j = 0; j < SCAN_I; ++j) {
        int idx = base + j;
        if (idx < n) rowptr[idx] = run;
        run += v[j];
    }
    if (threadIdx.x == SCAN_T - 1) bsum[blockIdx.x] = s[SCAN_T - 1];
}

__global__ __launch_bounds__(SCAN_T) void scan2_kernel(int* __restrict__ bsum, int nb) {
    __shared__ int s[SCAN_T];
    int v = (threadIdx.x < nb) ? bsum[threadIdx.x] : 0;
    s[threadIdx.x] = v;
    __syncthreads();
    for (int off = 1; off < SCAN_T; off <<= 1) {
        int t = (threadIdx.x >= off) ? s[threadIdx.x - off] : 0;
        __syncthreads();
        s[threadIdx.x] += t;
        __syncthreads();
    }
    if (threadIdx.x < nb) bsum[threadIdx.x] = s[threadIdx.x] - v;
}

__global__ void scan3_kernel(int* __restrict__ rowptr, int* __restrict__ cursor,
                             const int* __restrict__ bsum, int n, int nE) {
    int idx = blockIdx.x * blockDim.x + threadIdx.x;
    if (idx < n) {
        int val = rowptr[idx] + bsum[idx / SCAN_CHUNK];
        rowptr[idx] = val;
        cursor[idx] = val;
    }
    if (idx == 0) rowptr[n] = nE;
}

// XCD-bucketed scatter: block r=bid&7 handles dst range [r*n/8, (r+1)*n/8).
__global__ __launch_bounds__(256) void scatter_kernel(
    const int* __restrict__ ei, const float* __restrict__ ew,
    int* __restrict__ cursor, int2* __restrict__ srcw, int nE, int n) {
    int r = blockIdx.x & 7;
    int nslice = n >> 3;
    int lo = r * nslice;
    int hi = (r == 7) ? n : lo + nslice;
    int chunk = blockIdx.x >> 3;
    int nchunk = gridDim.x >> 3;
    for (int e = chunk * 256 + threadIdx.x; e < nE; e += nchunk * 256) {
        int dst = ei[nE + e];
        if (dst >= lo && dst < hi) {
            int pos = atomicAdd(&cursor[dst], 1);
            srcw[pos] = make_int2(ei[e], __float_as_int(ew[e]));
        }
    }
}

// ---------------- gated conv via CSR: 4 edges in flight per wave ----------------
__device__ inline void conv_fma(float* acc, uint4 u, float w) {
    acc[0] += __uint_as_float(u.x << 16) * w;
    acc[1] += __uint_as_float(u.x & 0xffff0000u) * w;
    acc[2] += __uint_as_float(u.y << 16) * w;
    acc[3] += __uint_as_float(u.y & 0xffff0000u) * w;
    acc[4] += __uint_as_float(u.z << 16) * w;
    acc[5] += __uint_as_float(u.z & 0xffff0000u) * w;
    acc[6] += __uint_as_float(u.w << 16) * w;
    acc[7] += __uint_as_float(u.w & 0xffff0000u) * w;
}

__global__ __launch_bounds__(256) void conv_csr_kernel(
    const bf16_t* __restrict__ xb, const int* __restrict__ rowptr,
    const int2* __restrict__ srcw, bf16_t* __restrict__ agg, int n) {
    int lane = threadIdx.x & 63;
    int d = (blockIdx.x * blockDim.x + threadIdx.x) >> 6;
    if (d >= n) return;
    int q = lane >> 4;
    int l = lane & 15;
    int beg = rowptr[d], end = rowptr[d + 1];

    float acc[8];
    #pragma unroll
    for (int i = 0; i < 8; ++i) acc[i] = 0.f;

    int e = beg + q;
    for (; e + 4 < end; e += 8) {
        int2 sw0 = srcw[e];
        int2 sw1 = srcw[e + 4];
        uint4 u0 = *(const uint4*)(xb + (size_t)sw0.x * H + l * 8);
        uint4 u1 = *(const uint4*)(xb + (size_t)sw1.x * H + l * 8);
        conv_fma(acc, u0, __int_as_float(sw0.y));
        conv_fma(acc, u1, __int_as_float(sw1.y));
    }
    if (e < end) {
        int2 sw = srcw[e];
        uint4 u = *(const uint4*)(xb + (size_t)sw.x * H + l * 8);
        conv_fma(acc, u, __int_as_float(sw.y));
    }

    #pragma unroll
    for (int i = 0; i < 8; ++i) {
        acc[i] += __shfl_xor(acc[i], 16);
        acc[i] += __shfl_xor(acc[i], 32);
    }
    if (q == 0) {
        bf16x8 r;
        #pragma unroll
        for (int i = 0; i < 8; ++i) r[i] = (bf16_t)acc[i];
        *(bf16x8*)(agg + (size_t)d * H + l * 8) = r;
    }
}

// ---------------- lin kernels: whole 32KB weight staged in LDS (swizzled) ----------------
// 16B granule (row, seg) -> byte row*256 + ((seg*16) ^ ((row&7)<<4))

__global__ __launch_bounds__(256) void lin_first_kernel(
    const float* __restrict__ A, const bf16_t* __restrict__ Bt,
    const float* __restrict__ bias, bf16_t* __restrict__ outb, int n) {
    __shared__ __align__(16) unsigned char wlds[32768];
    int tid = threadIdx.x;
    int wid = tid >> 6, lane = tid & 63;
    int r0 = (blockIdx.x * 4 + wid) * 32;
    int lrow = lane & 15, lq = lane >> 4, lk8 = lq * 8;

    #pragma unroll
    for (int i = 0; i < 8; ++i) {
        int g = i * 256 + tid;
        int row = g >> 4, seg = g & 15;
        uint4 v = *(const uint4*)(Bt + row * 128 + seg * 8);
        *(uint4*)(&wlds[row * 256 + ((seg * 16) ^ ((row & 7) << 4))]) = v;
    }

    bf16x8 a[2][4];
    for (int rt = 0; rt < 2; ++rt) {
        int row = r0 + rt * 16 + lrow;
        if (row >= n) row = n - 1;
        for (int t = 0; t < 4; ++t) a[rt][t] = load_a_frag_f32(A, row, t * 32 + lk8);
    }
    __syncthreads();

    for (int ct = 0; ct < 8; ++ct) {
        int c0 = ct * 16;
        f32x4 acc0 = {0.f, 0.f, 0.f, 0.f}, acc1 = {0.f, 0.f, 0.f, 0.f};
        int rbase = (c0 + lrow) * 256;
        int sw = (lrow & 7) << 4;
        #pragma unroll
        for (int t = 0; t < 4; ++t) {
            bf16x8 b = *(const bf16x8*)(&wlds[rbase + ((t * 64 + lq * 16) ^ sw)]);
            acc0 = __builtin_amdgcn_mfma_f32_16x16x32_bf16(a[0][t], b, acc0, 0, 0, 0);
            acc1 = __builtin_amdgcn_mfma_f32_16x16x32_bf16(a[1][t], b, acc1, 0, 0, 0);
        }
        int col = c0 + lrow;
        float bv = bias[col];
        for (int r = 0; r < 4; ++r) {
            int row0 = r0 + lq * 4 + r;
            if (row0 < n) outb[(size_t)row0 * H + col] = (bf16_t)(acc0[r] + bv);
            int row1 = row0 + 16;
            if (row1 < n) outb[(size_t)row1 * H + col] = (bf16_t)(acc1[r] + bv);
        }
    }
}

__global__ __launch_bounds__(256) void lin_mid_kernel(
    const bf16_t* __restrict__ A, const bf16_t* __restrict__ Bt,
    const float* __restrict__ bias, bf16_t* __restrict__ out, int n) {
    __shared__ __align__(16) unsigned char wlds[32768];
    int tid = threadIdx.x;
    int wid = tid >> 6, lane = tid & 63;
    int r0 = (blockIdx.x * 4 + wid) * 32;
    int lrow = lane & 15, lq = lane >> 4, lk8 = lq * 8;

    #pragma unroll
    for (int i = 0; i < 8; ++i) {
        int g = i * 256 + tid;
        int row = g >> 4, seg = g & 15;
        uint4 v = *(const uint4*)(Bt + row * 128 + seg * 8);
        *(uint4*)(&wlds[row * 256 + ((seg * 16) ^ ((row & 7) << 4))]) = v;
    }

    bf16x8 a[2][4];
    for (int rt = 0; rt < 2; ++rt) {
        int row = r0 + rt * 16 + lrow;
        if (row >= n) row = n - 1;
        for (int t = 0; t < 4; ++t)
            a[rt][t] = *(const bf16x8*)(A + (size_t)row * H + t * 32 + lk8);
    }
    __syncthreads();

    for (int ct = 0; ct < 8; ++ct) {
        int c0 = ct * 16;
        f32x4 acc0 = {0.f, 0.f, 0.f, 0.f}, acc1 = {0.f, 0.f, 0.f, 0.f};
        int rbase = (c0 + lrow) * 256;
        int sw = (lrow & 7) << 4;
        #pragma unroll
        for (int t = 0; t < 4; ++t) {
            bf16x8 b = *(const bf16x8*)(&wlds[rbase + ((t * 64 + lq * 16) ^ sw)]);
            acc0 = __builtin_amdgcn_mfma_f32_16x16x32_bf16(a[0][t], b, acc0, 0, 0, 0);
            acc1 = __builtin_amdgcn_mfma_f32_16x16x32_bf16(a[1][t], b, acc1, 0, 0, 0);
        }
        int col = c0 + lrow;
        float bv = bias[col];
        for (int r = 0; r < 4; ++r) {
            int row0 = r0 + lq * 4 + r;
            if (row0 < n) out[(size_t)row0 * H + col] = (bf16_t)(acc0[r] + bv);
            int row1 = row0 + 16;
            if (row1 < n) out[(size_t)row1 * H + col] = (bf16_t)(acc1[r] + bv);
        }
    }
}

// ---------------- GRU: column-tiled, LDS-persistent weights, 16-row waves,
//                  depth-2 software pipeline on the A-operand loads ----------------
template<bool LOGITS>
__global__ __launch_bounds__(256) void gru_kernel(
    const bf16_t* __restrict__ inp, const bf16_t* __restrict__ hidb,
    const bf16_t* __restrict__ Wih, const bf16_t* __restrict__ Whh,
    const float* __restrict__ bih, const float* __restrict__ bhh,
    bf16_t* __restrict__ out, const float* __restrict__ Wo,
    float* __restrict__ pl, int n) {
    __shared__ __align__(16) unsigned char wlds[12 * 4096];
    int tid = threadIdx.x;
    int wid = tid >> 6, lane = tid & 63;
    int cg = blockIdx.x & 3;
    int rb = blockIdx.x >> 2;
    int rstride = gridDim.x >> 2;
    int lrow = lane & 15, lq = lane >> 4, lk8 = lq * 8;

    // ---- stage 12 slabs (2 col-halves x {ir,iz,in,hr,hz,hn}) once ----
    int srow = tid >> 4, sseg = tid & 15;
    int s_src = srow * 128 + sseg * 8;
    int s_lds = srow * 256 + ((sseg * 16) ^ ((srow & 7) << 4));
    #pragma unroll
    for (int p = 0; p < 2; ++p) {
        #pragma unroll
        for (int s = 0; s < 3; ++s) {
            *(uint4*)(&wlds[(p * 6 + s) * 4096 + s_lds]) =
                *(const uint4*)(Wih + (size_t)(s * 128 + cg * 32 + p * 16) * 128 + s_src);
            *(uint4*)(&wlds[(p * 6 + 3 + s) * 4096 + s_lds]) =
                *(const uint4*)(Whh + (size_t)(s * 128 + cg * 32 + p * 16) * 128 + s_src);
        }
    }
    __syncthreads();

    // per-lane constants (loop-invariant)
    int colA = cg * 32 + lrow, colB = colA + 16;
    float birA = bih[colA], bizA = bih[128 + colA], binA = bih[256 + colA];
    float bhrA = bhh[colA], bhzA = bhh[128 + colA], bhnA = bhh[256 + colA];
    float birB = bih[colB], bizB = bih[128 + colB], binB = bih[256 + colB];
    float bhrB = bhh[colB], bhzB = bhh[128 + colB], bhnB = bhh[256 + colB];
    float w0A = 0.f, w1A = 0.f, w0B = 0.f, w1B = 0.f;
    if (LOGITS) {
        float2 wa = *(const float2*)(Wo + colA * 2); w0A = wa.x; w1A = wa.y;
        float2 wb = *(const float2*)(Wo + colB * 2); w0B = wb.x; w1B = wb.y;
    }
    // hoisted identity B-fragments
    bf16x8 bidA, bidB;
    #pragma unroll
    for (int j = 0; j < 8; ++j) {
        bidA[j] = (bf16_t)((lq == (lrow >> 3) && j == (lrow & 7)) ? 1.f : 0.f);
        int ix = 16 + lrow;
        bidB[j] = (bf16_t)((lq == (ix >> 3) && j == (ix & 7)) ? 1.f : 0.f);
    }
    int rbase = lrow * 256;
    int swz = (lrow & 7) << 4;

    int nrt = (n + 63) >> 6;
    if (rb >= nrt) return;

    // ---- prologue: load first tile ----
    bf16x8 ai[4], ah[4], nai[4], nah[4];
    {
        int rowl = rb * 64 + wid * 16 + lrow;
        if (rowl >= n) rowl = n - 1;
        #pragma unroll
        for (int t = 0; t < 4; ++t) {
            ai[t] = *(const bf16x8*)(inp  + (size_t)rowl * H + t * 32 + lk8);
            ah[t] = *(const bf16x8*)(hidb + (size_t)rowl * H + t * 32 + lk8);
        }
    }

    for (int rbi = rb; rbi < nrt; rbi += rstride) {
        // ---- issue next tile's loads (hidden under this tile's compute) ----
        {
            int nx = rbi + rstride;
            int rowl = (nx < nrt) ? nx * 64 + wid * 16 + lrow : 0;
            if (rowl >= n) rowl = n - 1;
            #pragma unroll
            for (int t = 0; t < 4; ++t) {
                nai[t] = *(const bf16x8*)(inp  + (size_t)rowl * H + t * 32 + lk8);
                nah[t] = *(const bf16x8*)(hidb + (size_t)rowl * H + t * 32 + lk8);
            }
        }

        int r0 = rbi * 64 + wid * 16;
        float s0[4], s1[4];
        if (LOGITS) {
            #pragma unroll
            for (int r = 0; r < 4; ++r) { s0[r] = 0.f; s1[r] = 0.f; }
        }

        #pragma unroll
        for (int p = 0; p < 2; ++p) {
            float b_ir = p ? birB : birA, b_iz = p ? bizB : bizA, b_in = p ? binB : binA;
            float b_hr = p ? bhrB : bhrA, b_hz = p ? bhzB : bhzA, b_hn = p ? bhnB : bhnA;
            // bias folded into accumulator init
            f32x4 air = {b_ir, b_ir, b_ir, b_ir}, aiz = {b_iz, b_iz, b_iz, b_iz},
                  ain = {b_in, b_in, b_in, b_in}, ahr = {b_hr, b_hr, b_hr, b_hr},
                  ahz = {b_hz, b_hz, b_hz, b_hz}, ahn = {b_hn, b_hn, b_hn, b_hn};
            const unsigned char* wb_ = &wlds[p * 6 * 4096];
            #pragma unroll
            for (int t = 0; t < 4; ++t) {
                int roff = rbase + ((t * 64 + lq * 16) ^ swz);
                bf16x8 bir = *(const bf16x8*)(wb_ + 0 * 4096 + roff);
                bf16x8 biz = *(const bf16x8*)(wb_ + 1 * 4096 + roff);
                bf16x8 bin = *(const bf16x8*)(wb_ + 2 * 4096 + roff);
                bf16x8 bhr = *(const bf16x8*)(wb_ + 3 * 4096 + roff);
                bf16x8 bhz = *(const bf16x8*)(wb_ + 4 * 4096 + roff);
                bf16x8 bhn = *(const bf16x8*)(wb_ + 5 * 4096 + roff);
                air = __builtin_amdgcn_mfma_f32_16x16x32_bf16(ai[t], bir, air, 0, 0, 0);
                aiz = __builtin_amdgcn_mfma_f32_16x16x32_bf16(ai[t], biz, aiz, 0, 0, 0);
                ain = __builtin_amdgcn_mfma_f32_16x16x32_bf16(ai[t], bin, ain, 0, 0, 0);
                ahr = __builtin_amdgcn_mfma_f32_16x16x32_bf16(ah[t], bhr, ahr, 0, 0, 0);
                ahz = __builtin_amdgcn_mfma_f32_16x16x32_bf16(ah[t], bhz, ahz, 0, 0, 0);
                ahn = __builtin_amdgcn_mfma_f32_16x16x32_bf16(ah[t], bhn, ahn, 0, 0, 0);
            }
            f32x4 zz = {0.f, 0.f, 0.f, 0.f};
            f32x4 hc = __builtin_amdgcn_mfma_f32_16x16x32_bf16(ah[cg], p ? bidB : bidA, zz, 0, 0, 0);

            float w0 = p ? w0B : w0A, w1 = p ? w1B : w1A;
            int col = cg * 32 + p * 16 + lrow;
            #pragma unroll
            for (int r = 0; r < 4; ++r) {
                int row = r0 + lq * 4 + r;
                float rg = 1.f / (1.f + __expf(-(air[r] + ahr[r])));
                float zg = 1.f / (1.f + __expf(-(aiz[r] + ahz[r])));
                float xx = ain[r] + rg * ahn[r];
                float ng = 2.f / (1.f + __expf(-2.f * xx)) - 1.f;   // tanh
                float hout = (1.f - zg) * ng + zg * hc[r];
                if (LOGITS) {
                    s0[r] += hout * w0;
                    s1[r] += hout * w1;
                } else if (row < n) {
                    out[(size_t)row * H + col] = (bf16_t)hout;
                }
            }
        }

        if (LOGITS) {
            #pragma unroll
            for (int m = 1; m < 16; m <<= 1) {
                #pragma unroll
                for (int r = 0; r < 4; ++r) {
                    s0[r] += __shfl_xor(s0[r], m);
                    s1[r] += __shfl_xor(s1[r], m);
                }
            }
            if (lrow == 0) {
                #pragma unroll
                for (int r = 0; r < 4; ++r) {
                    int row = r0 + lq * 4 + r;
                    if (row < n) {
                        pl[(size_t)row * 8 + cg * 2]     = s0[r];
                        pl[(size_t)row * 8 + cg * 2 + 1] = s1[r];
                    }
                }
            }
        }

        // ---- rotate pipeline registers ----
        #pragma unroll
        for (int t = 0; t < 4; ++t) { ai[t] = nai[t]; ah[t] = nah[t]; }
    }
}

// ---------------- finalize: sum col-group partials, bias, log_softmax ----------------
__global__ void head_finalize(const float* __restrict__ pl, const float* __restrict__ bo,
                              float* __restrict__ outp, int n) {
    int row = blockIdx.x * blockDim.x + threadIdx.x;
    if (row >= n) return;
    const float4* p = (const float4*)(pl + (size_t)row * 8);
    float4 a = p[0], b = p[1];
    float l0 = a.x + a.z + b.x + b.z + bo[0];
    float l1 = a.y + a.w + b.y + b.w + bo[1];
    float mx = fmaxf(l0, l1);
    float lse = mx + __logf(__expf(l0 - mx) + __expf(l1 - mx));
    outp[(size_t)row * 2]     = l0 - lse;
    outp[(size_t)row * 2 + 1] = l1 - lse;
}

extern "C" void kernel_launch(void* const* d_in, const int* in_sizes, int n_in,
                              void* d_out, int out_size, void* d_ws, size_t ws_size,
                              hipStream_t stream) {
    const float* x   = (const float*)d_in[0];
    const int*   ei  = (const int*)d_in[1];
    const float* ew  = (const float*)d_in[2];
    const float* Wf  = (const float*)d_in[3];
    const float* bf  = (const float*)d_in[4];
    const float* Wih = (const float*)d_in[5];
    const float* bih = (const float*)d_in[6];
    const float* Whh = (const float*)d_in[7];
    const float* bhh = (const float*)d_in[8];
    const float* Wl1 = (const float*)d_in[9];
    const float* bl1 = (const float*)d_in[10];
    const float* Wo  = (const float*)d_in[11];
    const float* bo  = (const float*)d_in[12];

    int n  = in_sizes[0] / H;     // 100000
    int nE = in_sizes[2];         // 1600000

    bf16_t* hbufb = (bf16_t*)d_ws;                        // [n][H] hidden
    bf16_t* b1b   = hbufb + (size_t)n * H;                // [n][H] conv1 out / conv2 out
    bf16_t* b2b   = b1b + (size_t)n * H;                  // [n][H] lin1 out
    bf16_t* b3b   = b2b + (size_t)n * H;                  // [n][H] gru1 out
    float*  pl    = (float*)(b3b + (size_t)n * H);        // [n][8] logit partials
    bf16_t* wfT   = (bf16_t*)(pl + (size_t)n * 8);
    bf16_t* wih   = wfT + 128 * 128;
    bf16_t* whh   = wih + 384 * 128;
    bf16_t* wl1T  = whh + 384 * 128;
    int* deg    = (int*)(wl1T + 128 * 128);               // [n]
    int* rowptr = deg + n;                                // [n+1]
    int* cursor = rowptr + (n + 1);                       // [n]
    int2* srcw  = (int2*)((char*)(cursor + n) + ((size_t)(-(intptr_t)(cursor + n)) & 7)); // [nE]

    int gemmGrid = (n + 127) / 128;
    int nScanBlocks = (n + SCAN_CHUNK - 1) / SCAN_CHUNK;

    // ---- weights + CSR build ----
    prep_weights<<<192, 256, 0, stream>>>(Wf, Wih, Whh, Wl1, wfT, wih, whh, wl1T);
    hipMemsetAsync(deg, 0, (size_t)n * sizeof(int), stream);
    hist_kernel<<<(nE + 255) / 256, 256, 0, stream>>>(ei, deg, nE);
    scan1_kernel<<<nScanBlocks, SCAN_T, 0, stream>>>(deg, rowptr, cursor, n);
    scan2_kernel<<<1, SCAN_T, 0, stream>>>(cursor, nScanBlocks);
    scan3_kernel<<<(n + 255) / 256, 256, 0, stream>>>(rowptr, deg, cursor, n, nE);
    scatter_kernel<<<2048, 256, 0, stream>>>(ei, ew, deg, srcw, nE, n);

    // ---- pipeline ----
    lin_first_kernel<<<gemmGrid, 256, 0, stream>>>(x, wfT, bf, hbufb, n);
    conv_csr_kernel<<<(n + 3) / 4, 256, 0, stream>>>(hbufb, rowptr, srcw, b1b, n);
    gru_kernel<false><<<2048, 256, 0, stream>>>(b1b, hbufb, wih, whh, bih, bhh,
                                                b3b, nullptr, nullptr, n);
    lin_mid_kernel<<<gemmGrid, 256, 0, stream>>>(b3b, wl1T, bl1, b2b, n);
    conv_csr_kernel<<<(n + 3) / 4, 256, 0, stream>>>(b2b, rowptr, srcw, b1b, n);
    gru_kernel<true><<<2048, 256, 0, stream>>>(b1b, hbufb, wih, whh, bih, bhh,
                                               nullptr, Wo, pl, n);
    head_finalize<<<(n + 255) / 256, 256, 0, stream>>>(pl, bo, (float*)d_out, n);
}